// Round 7
// baseline (674.827 us; speedup 1.0000x reference)
//
#include <hip/hip_runtime.h>
#include <cstdint>
#include <cstddef>

// SAGE-LSTM R18: lean 8-trans cell, liveness-bounded, spill-free at (512,4).
// R17 post-mortem: the 7-trans common-denominator cell held ~8 extra live
// temps -> blew the 128-total-reg budget -> 137MB scratch spill (WRITE_SIZE)
// -> 263us despite VALU issue dropping 135->118us. Occupancy tiers cliff at
// 128/256 regs, so the fix must FIT 128, not relax it.
// R18 cell keeps R16's tight exp->rcp chains but folds only naturally-shared
// denominators:
//   ig = sig(i)*tanh(g) = (1-Eg)*rcp((1+Ei)(1+Eg))   (2 exp + 1 rcp)
//   fv = sig(f)         = rcp(1+Ef)                   (1 exp + 1 rcp)
//   h  = sig(o)*tanh(c) = (1-Ec)*rcp((1+Eo)(1+Ec))   (2 exp + 1 rcp)
// 8 trans/elem (R16: 10), peak ~3 co-live temps (R16-level). Tally ~122<=128.

constexpr int IN  = 128;
constexpr int DEG = 16;

typedef short bf16x8 __attribute__((ext_vector_type(8)));
typedef float f32x4  __attribute__((ext_vector_type(4)));
typedef float f32x16 __attribute__((ext_vector_type(16)));
typedef unsigned int u32x4 __attribute__((ext_vector_type(4)));
typedef unsigned int u32x2 __attribute__((ext_vector_type(2)));

__device__ __forceinline__ float fsigmoid(float x) {
    float e = __expf(-x);
    return __builtin_amdgcn_rcpf(1.0f + e);
}
__device__ __forceinline__ uint32_t pack2bf16(float a, float b) {
    uint32_t ua = __float_as_uint(a) + 0x8000u;
    uint32_t ub = __float_as_uint(b) + 0x8000u;
    return (ua >> 16) | (ub & 0xFFFF0000u);
}

// lean LSTM cell: 5 exp + 3 rcp, max ~3 co-live temps. Updates c, returns h.
__device__ __forceinline__ float cell_h(float ai, float af, float ag, float ao,
                                        float& c) {
    float Ei = __expf(-ai);
    float Eg = __expf(-2.0f * ag);
    float ig = (1.0f - Eg) * __builtin_amdgcn_rcpf((1.0f + Ei) * (1.0f + Eg));
    float fv = fsigmoid(af);
    float cv = __fmaf_rn(fv, c, ig);
    c = cv;
    float Eo = __expf(-ao);
    float Ec = __expf(-2.0f * cv);
    return (1.0f - Ec) * __builtin_amdgcn_rcpf((1.0f + Eo) * (1.0f + Ec));
}

// ---------- prep kernels ----------

__global__ void k_cast_bf16(const float* __restrict__ src, ushort* __restrict__ dst, int n) {
    int i = (blockIdx.x * blockDim.x + threadIdx.x) * 4;
    if (i + 3 < n) {
        float4 v = *(const float4*)(src + i);
        uint2 d; d.x = pack2bf16(v.x, v.y); d.y = pack2bf16(v.z, v.w);
        *(uint2*)(dst + i) = d;
    } else {
        for (int k = i; k < n; ++k)
            dst[k] = (ushort)((__float_as_uint(src[k]) + 0x8000u) >> 16);
    }
}

// Pack all 4 [512 x 128] gate weights into MFMA fragment order.
// ih (which 0,2): 32x32x16 B-frag (consumed by k_xu).
// hh (which 1,3): 16x16x32 frag (A-operand in k_lstm_fused):
//   frag[((g*8+w)*4+ks)*64 + lane]; row jj = g*128+w*16+(lane&15),
//   k = ks*32+(lane>>4)*8+j.
__global__ void k_pack_all(const float* __restrict__ w0, u32x4* __restrict__ f0,
                           const float* __restrict__ w1, u32x4* __restrict__ f1,
                           const float* __restrict__ w2, u32x4* __restrict__ f2,
                           const float* __restrict__ w3, u32x4* __restrict__ f3) {
    int gt = blockIdx.x * 256 + threadIdx.x;     // 0..32767
    int which = gt >> 13;
    int tid  = gt & 8191;
    const float* wsrc = (which == 0) ? w0 : (which == 1) ? w1 : (which == 2) ? w2 : w3;
    u32x4* frag = (which == 0) ? f0 : (which == 1) ? f1 : (which == 2) ? f2 : f3;
    int lane = tid & 63;
    float v[8];
    if ((which & 1) == 0) {
        int tile = (tid >> 6) & 15;
        int kst  = tid >> 10;
        int n     = tile * 32 + (lane & 31);
        int kbase = kst * 16 + (lane >> 5) * 8;
#pragma unroll
        for (int j = 0; j < 8; ++j) v[j] = wsrc[n * 128 + kbase + j];
    } else {
        int f  = tid >> 6;            // 0..127
        int ks = f & 3;
        int w8 = (f >> 2) & 7;
        int g  = f >> 5;
        int jj    = g * 128 + w8 * 16 + (lane & 15);
        int kbase = ks * 32 + (lane >> 4) * 8;
#pragma unroll
        for (int j = 0; j < 8; ++j) v[j] = wsrc[jj * 128 + kbase + j];
    }
    u32x4 d;
    d.x = pack2bf16(v[0], v[1]);
    d.y = pack2bf16(v[2], v[3]);
    d.z = pack2bf16(v[4], v[5]);
    d.w = pack2bf16(v[6], v[7]);
    frag[tid] = d;
}

// Pack output-linear weights as A-frags over K=256 concat [Wself ; Wneigh].
__global__ void k_pack_out(const float* __restrict__ ws1, const float* __restrict__ wn1,
                           u32x4* __restrict__ f1,
                           const float* __restrict__ ws2, const float* __restrict__ wn2,
                           u32x4* __restrict__ f2) {
    int t = blockIdx.x * 256 + threadIdx.x;   // 0..6143
    int lane = t & 63;
    int row  = lane & 15;
    int kb   = (lane >> 4) * 8;
    float v[8];
    const float* ws; const float* wn; u32x4* dst; int p;
    if (t < 4096) { ws = ws1; wn = wn1; dst = f1; p = t; }
    else          { ws = ws2; wn = wn2; dst = f2; p = t - 4096; }
    int ks  = (p >> 6) & 7;
    int och = (p >> 9) * 16 + row;
    int kbase = ks * 32 + kb;
#pragma unroll
    for (int j = 0; j < 8; ++j) {
        int k = kbase + j;
        v[j] = (k < 128) ? ws[och * 128 + k] : wn[och * 128 + k - 128];
    }
    u32x4 d;
    d.x = pack2bf16(v[0], v[1]);
    d.y = pack2bf16(v[2], v[3]);
    d.z = pack2bf16(v[4], v[5]);
    d.w = pack2bf16(v[6], v[7]);
    dst[p] = d;
}

// ---------- kernel A: Xu = x @ W_ih^T + (b_ih+b_hh), gate-quad row store ----------
__global__ __launch_bounds__(256, 2) void k_xu(
    const ushort* __restrict__ x,       // [N,128] bf16
    const u32x4*  __restrict__ wih,     // 8192 B-frags (32x32 layout)
    const float*  __restrict__ b_ih,    // [512]
    const float*  __restrict__ b_hh,    // [512]
    u32x2*        __restrict__ xu,      // [Nceil][128] u32x2 (1KB rows)
    int N)
{
    __shared__ u32x4 a_buf[16][66];

    const int tid   = threadIdx.x;
    const int lane  = tid & 63;
    const int w     = tid >> 6;
    const int mrow  = lane & 31;
    const int khalf = lane >> 5;
    const int node0 = blockIdx.x * 64;

    u32x4 wreg[8][4];
#pragma unroll
    for (int kst = 0; kst < 8; ++kst)
#pragma unroll
        for (int g = 0; g < 4; ++g)
            wreg[kst][g] = wih[(kst * 16 + g * 4 + w) * 64 + lane];

    float binit[4];
#pragma unroll
    for (int g = 0; g < 4; ++g) {
        int jj = g * 128 + w * 32 + mrow;
        binit[g] = b_ih[jj] + b_hh[jj];
    }

    {
        int m_st = tid >> 2, c4 = tid & 3;
        int gn = node0 + m_st; if (gn >= N) gn = N - 1;
        const u32x4* src = (const u32x4*)(x + (size_t)gn * IN);
#pragma unroll
        for (int q = 0; q < 4; ++q) {
            int kg = q * 4 + c4;
            a_buf[kg][m_st] = src[kg];
        }
    }
    __syncthreads();

    const int coff = w * 32 + mrow;
#pragma unroll 1
    for (int Mt = 0; Mt < 2; ++Mt) {
        f32x16 acc[4];
#pragma unroll
        for (int g = 0; g < 4; ++g)
#pragma unroll
            for (int r = 0; r < 16; ++r) acc[g][r] = binit[g];

#pragma unroll
        for (int kst = 0; kst < 8; ++kst) {
            bf16x8 a = __builtin_bit_cast(bf16x8, a_buf[kst * 2 + khalf][Mt * 32 + mrow]);
#pragma unroll
            for (int g = 0; g < 4; ++g)
                acc[g] = __builtin_amdgcn_mfma_f32_32x32x16_bf16(
                    a, __builtin_bit_cast(bf16x8, wreg[kst][g]), acc[g], 0, 0, 0);
        }

#pragma unroll
        for (int r = 0; r < 16; ++r) {
            int m = Mt * 32 + (r & 3) + 8 * (r >> 2) + 4 * khalf;
            u32x2 d;
            d.x = pack2bf16(acc[0][r], acc[1][r]);
            d.y = pack2bf16(acc[2][r], acc[3][r]);
            xu[(size_t)(node0 + m) * 128 + coff] = d;
        }
    }
}

// ---------- kernel B: recurrent LSTM (C^T) + fused output linear ----------
// wave w owns channels [w*16,w*16+16) of ALL 4 gates; C^T: row = channel
// (l4*4+q), col = node. Lane owns 4 ADJACENT channels of 1 node per tile ->
// shfl-free h pack. h LDS: [node][ch] bf16, row stride 272B (17x16B).
template <int NOUT, int ACT, typename OutT>
__global__ __launch_bounds__(512, 4) void k_lstm_fused(
    const u32x2*  __restrict__ xu,      // 1KB gate-quad rows
    const int*    __restrict__ nbr,     // [N,16]
    const u32x4*  __restrict__ whh,     // 128 frags (A-operand)
    const u32x4*  __restrict__ wout,    // epilogue A-frags (K=256 concat)
    const float*  __restrict__ bout,    // [NOUT]
    const ushort* __restrict__ x_in,    // [N,128] bf16 (self input)
    OutT*         __restrict__ out,     // [N,NOUT]
    int N)
{
    constexpr int HSTR = 272;                        // 17 x 16B, b128-aligned
    __shared__ alignas(16) char h_lds[2][32 * HSTR]; // 2 x 8.5KB
    __shared__ uint32_t idxs[DEG * 32];              // prescaled byte offsets

    const int tid  = threadIdx.x;
    const int lane = tid & 63;
    const int w    = tid >> 6;
    const int col  = lane & 15;
    const int l4   = lane >> 4;
    const int node0 = blockIdx.x * 32;

    {
        int m = tid & 31, t = tid >> 5;
        int gn = node0 + m; if (gn >= N) gn = N - 1;
        idxs[t * 32 + m] = (uint32_t)nbr[gn * DEG + t] << 10;
    }
    for (int i = tid; i < 32 * HSTR / 16; i += 512)
        ((u32x4*)h_lds[0])[i] = u32x4{0u, 0u, 0u, 0u};

    // W_hh A-frags: 64 regs
    u32x4 wreg[4][4];
#pragma unroll
    for (int g = 0; g < 4; ++g)
#pragma unroll
        for (int ks = 0; ks < 4; ++ks)
            wreg[g][ks] = whh[((g * 8 + w) * 4 + ks) * 64 + lane];

    float cst[8];
#pragma unroll
    for (int r = 0; r < 8; ++r) cst[r] = 0.0f;

    const char* xu_c = (const char*)xu;
    const uint32_t goff = (uint32_t)(w * 128 + l4 * 32);  // slice byte in xu row
    const int rd0 = col * HSTR + l4 * 16;                 // + ks*64 + mt*16*HSTR
    const int wr0 = col * HSTR + w * 32 + l4 * 8;         // + mt*16*HSTR

    __syncthreads();   // idxs + h(-1) zeros visible

    // prologue gather (step 0): 32B contiguous per (node, ch-quad)
    u32x4 vv[4];
    {
        const char* p0 = xu_c + idxs[col] + goff;
        const char* p1 = xu_c + idxs[16 + col] + goff;
        vv[0] = *(const u32x4*)(p0);
        vv[1] = *(const u32x4*)(p0 + 16);
        vv[2] = *(const u32x4*)(p1);
        vv[3] = *(const u32x4*)(p1 + 16);
    }

#pragma unroll 1
    for (int t = 0; t < DEG; ++t) {
        const char* hr = h_lds[t & 1];
        char*       hw = h_lds[(t + 1) & 1];

#pragma unroll
        for (int mt = 0; mt < 2; ++mt) {
            // ---- acc init: C^T element (ch = w*16+l4*4+q, node = mt*16+col)
            f32x4 acc[4];
#pragma unroll
            for (int q = 0; q < 4; ++q) {
                uint32_t px = vv[mt * 2 + (q >> 1)][(q & 1) * 2];
                uint32_t py = vv[mt * 2 + (q >> 1)][(q & 1) * 2 + 1];
                acc[0][q] = __uint_as_float(px << 16);
                acc[1][q] = __uint_as_float(px & 0xFFFF0000u);
                acc[2][q] = __uint_as_float(py << 16);
                acc[3][q] = __uint_as_float(py & 0xFFFF0000u);
            }

            // ---- prefetch next step once vv fully consumed
            if (mt == 1 && t + 1 < DEG) {
                const char* p0 = xu_c + idxs[(t + 1) * 32 + col] + goff;
                const char* p1 = xu_c + idxs[(t + 1) * 32 + 16 + col] + goff;
                vv[0] = *(const u32x4*)(p0);
                vv[1] = *(const u32x4*)(p0 + 16);
                vv[2] = *(const u32x4*)(p1);
                vv[3] = *(const u32x4*)(p1 + 16);
            }

            // ---- MFMA C^T: A = W_hh frags, B = h(t-1) from LDS
#pragma unroll
            for (int ks = 0; ks < 4; ++ks) {
                bf16x8 b = *(const bf16x8*)(hr + mt * 16 * HSTR + rd0 + ks * 64);
#pragma unroll
                for (int g = 0; g < 4; ++g)
                    acc[g] = __builtin_amdgcn_mfma_f32_16x16x32_bf16(
                        __builtin_bit_cast(bf16x8, wreg[g][ks]), b, acc[g], 0, 0, 0);
            }

            // ---- lean cell update (8 trans/elem) + shfl-free packed h write
            float hv[4];
#pragma unroll
            for (int q = 0; q < 4; ++q)
                hv[q] = cell_h(acc[0][q], acc[1][q], acc[2][q], acc[3][q],
                               cst[mt * 4 + q]);
            u32x2 hp;
            hp.x = pack2bf16(hv[0], hv[1]);
            hp.y = pack2bf16(hv[2], hv[3]);
            *(u32x2*)(hw + mt * 16 * HSTR + wr0) = hp;
        }

        __syncthreads();   // h(t) visible; WAR-safe via dbuf (1 barrier/step)
    }

    // ---- fused output linear: out = act([x|h] @ [Ws;Wn]^T + b), C^T MFMA
    {
        const char* hf = h_lds[0];                 // h(15) parity: buf[16&1]
        constexpr int TILES = (NOUT == 128) ? 2 : 1;
        const int otile = (NOUT == 128) ? w : (w & 3);
        const int mtb   = (NOUT == 128) ? 0 : (w >> 2);
        const int och0  = otile * 16 + l4 * 4;
        const float4 bq = *(const float4*)(bout + och0);

#pragma unroll
        for (int mi = 0; mi < TILES; ++mi) {
            const int mt = mtb + mi;
            const int gn = node0 + mt * 16 + col;
            const int gx = (gn < N) ? gn : (N - 1);
            f32x4 acc = {bq.x, bq.y, bq.z, bq.w};
#pragma unroll
            for (int ks = 0; ks < 8; ++ks) {
                u32x4 af = wout[(otile * 8 + ks) * 64 + lane];
                bf16x8 bf_;
                if (ks < 4)
                    bf_ = *(const bf16x8*)((const char*)x_in + (size_t)gx * 256 +
                                           ks * 64 + l4 * 16);
                else
                    bf_ = *(const bf16x8*)(hf + mt * 16 * HSTR + col * HSTR +
                                           (ks - 4) * 64 + l4 * 16);
                acc = __builtin_amdgcn_mfma_f32_16x16x32_bf16(
                    __builtin_bit_cast(bf16x8, af), bf_, acc, 0, 0, 0);
            }
            if (gn < N) {
                float av[4];
#pragma unroll
                for (int q = 0; q < 4; ++q)
                    av[q] = (ACT == 0) ? fmaxf(acc[q], 0.0f) : fsigmoid(acc[q]);
                if constexpr (sizeof(OutT) == 2) {
                    u32x2 o;
                    o.x = pack2bf16(av[0], av[1]);
                    o.y = pack2bf16(av[2], av[3]);
                    *(u32x2*)((ushort*)out + (size_t)gn * NOUT + och0) = o;
                } else {
                    f32x4 o = {av[0], av[1], av[2], av[3]};
                    *(f32x4*)((float*)out + (size_t)gn * NOUT + och0) = o;
                }
            }
        }
    }
}

extern "C" void kernel_launch(void* const* d_in, const int* in_sizes, int n_in,
                              void* d_out, int out_size, void* d_ws, size_t ws_size,
                              hipStream_t stream)
{
    const float* feats    = (const float*)d_in[0];
    const int*   nbr      = (const int*)  d_in[1];
    const float* w_ih1    = (const float*)d_in[2];
    const float* w_hh1    = (const float*)d_in[3];
    const float* b_ih1    = (const float*)d_in[4];
    const float* b_hh1    = (const float*)d_in[5];
    const float* w_self1  = (const float*)d_in[6];
    const float* w_neigh1 = (const float*)d_in[7];
    const float* b1       = (const float*)d_in[8];
    const float* w_ih2    = (const float*)d_in[9];
    const float* w_hh2    = (const float*)d_in[10];
    const float* b_ih2    = (const float*)d_in[11];
    const float* b_hh2    = (const float*)d_in[12];
    const float* w_self2  = (const float*)d_in[13];
    const float* w_neigh2 = (const float*)d_in[14];
    const float* b2       = (const float*)d_in[15];
    float* out = (float*)d_out;

    const int N = in_sizes[0] / IN;   // 50000
    const long long Nceil = (N + 63) & ~63LL;

    char* ws = (char*)d_ws;
    size_t off = 0;
    auto alloc = [&](size_t bytes) -> void* {
        void* p = (void*)(ws + off);
        off += (bytes + 255) & ~(size_t)255;
        return p;
    };
    u32x4*  wfrag_ih1 = (u32x4*)alloc(8192 * 16);
    u32x4*  wfrag_hh1 = (u32x4*)alloc(8192 * 16);
    u32x4*  wfrag_ih2 = (u32x4*)alloc(8192 * 16);
    u32x4*  wfrag_hh2 = (u32x4*)alloc(8192 * 16);
    u32x4*  wofrag1   = (u32x4*)alloc(4096 * 16);   // 64KB epilogue A-frags L1
    u32x4*  wofrag2   = (u32x4*)alloc(2048 * 16);   // 32KB epilogue A-frags L2
    ushort* feats_bf  = (ushort*)alloc((size_t)N * 128 * 2);
    ushort* out1      = (ushort*)alloc((size_t)N * 128 * 2);
    u32x2*  xu_buf    = (u32x2*)alloc((size_t)Nceil * 128 * 8);   // 51.25MB

    // prep
    k_pack_all<<<dim3(128), dim3(256), 0, stream>>>(w_ih1, wfrag_ih1, w_hh1, wfrag_hh1,
                                                    w_ih2, wfrag_ih2, w_hh2, wfrag_hh2);
    k_pack_out<<<dim3(24), dim3(256), 0, stream>>>(w_self1, w_neigh1, wofrag1,
                                                   w_self2, w_neigh2, wofrag2);
    k_cast_bf16<<<dim3((N * 128 / 4 + 255) / 256), dim3(256), 0, stream>>>(feats, feats_bf, N * 128);

    const int nblk64 = (int)(Nceil / 64);
    const int nblk32 = (N + 31) / 32;

    // layer 1
    k_xu<<<dim3(nblk64), dim3(256), 0, stream>>>(feats_bf, wfrag_ih1, b_ih1, b_hh1, xu_buf, N);
    k_lstm_fused<128, 0, ushort><<<dim3(nblk32), dim3(512), 0, stream>>>(
        xu_buf, nbr, wfrag_hh1, wofrag1, b1, feats_bf, out1, N);

    // layer 2
    k_xu<<<dim3(nblk64), dim3(256), 0, stream>>>(out1, wfrag_ih2, b_ih2, b_hh2, xu_buf, N);
    k_lstm_fused<64, 1, float><<<dim3(nblk32), dim3(512), 0, stream>>>(
        xu_buf, nbr, wfrag_hh2, wofrag2, b2, out1, out, N);
}

// Round 9
// 516.733 us; speedup vs baseline: 1.3059x; 1.3059x over previous
//
#include <hip/hip_runtime.h>
#include <cstdint>
#include <cstddef>

// SAGE-LSTM R20: R19 with the exp2 builtin fixed (__exp2f does not exist in
// this toolchain; use __builtin_amdgcn_exp2f -> v_exp_f32 = 2^x directly).
// Design (R19): R16 verbatim cell + exp2 weight-prescale. __expf(x) compiles
// to v_mul(log2e)+v_exp; fold the muls into the packed weights (gate i,f,o
// rows x log2e; gate g rows x 2log2e; biases likewise). Cell uses exp2(-y)
// with the neg folded into the input modifier -> 4 of 5 per-element v_muls
// deleted; tanh(c) keeps one. Strictly-deleting mutation of R16's verified
// graph -> spill outcome must match R16 (28MB WRITE_SIZE).

constexpr int IN  = 128;
constexpr int DEG = 16;
#define LOG2E      1.4426950408889634f
#define TWO_LOG2E  2.8853900817779268f

typedef short bf16x8 __attribute__((ext_vector_type(8)));
typedef float f32x4  __attribute__((ext_vector_type(4)));
typedef float f32x16 __attribute__((ext_vector_type(16)));
typedef unsigned int u32x4 __attribute__((ext_vector_type(4)));
typedef unsigned int u32x2 __attribute__((ext_vector_type(2)));

__device__ __forceinline__ float fsigmoid(float x) {   // unscaled input
    float e = __expf(-x);
    return __builtin_amdgcn_rcpf(1.0f + e);
}
// sigma(x) with y = x*log2e pre-scaled into the weights
__device__ __forceinline__ float sig2(float y) {
    float e = __builtin_amdgcn_exp2f(-y);
    return __builtin_amdgcn_rcpf(1.0f + e);
}
// tanh(x) with y = 2x*log2e pre-scaled
__device__ __forceinline__ float tanh2(float y) {
    float e = __builtin_amdgcn_exp2f(-y);
    return __fmaf_rn(2.0f, __builtin_amdgcn_rcpf(1.0f + e), -1.0f);
}
__device__ __forceinline__ uint32_t pack2bf16(float a, float b) {
    uint32_t ua = __float_as_uint(a) + 0x8000u;
    uint32_t ub = __float_as_uint(b) + 0x8000u;
    return (ua >> 16) | (ub & 0xFFFF0000u);
}

// ---------- prep kernels ----------

__global__ void k_cast_bf16(const float* __restrict__ src, ushort* __restrict__ dst, int n) {
    int i = (blockIdx.x * blockDim.x + threadIdx.x) * 4;
    if (i + 3 < n) {
        float4 v = *(const float4*)(src + i);
        uint2 d; d.x = pack2bf16(v.x, v.y); d.y = pack2bf16(v.z, v.w);
        *(uint2*)(dst + i) = d;
    } else {
        for (int k = i; k < n; ++k)
            dst[k] = (ushort)((__float_as_uint(src[k]) + 0x8000u) >> 16);
    }
}

// Pack all 4 [512 x 128] gate weights into MFMA fragment order, PRE-SCALED:
// gate rows i,f,o (rows 0..255, 384..511) x log2e; gate g (256..383) x 2log2e.
// ih (which 0,2): 32x32x16 B-frag (consumed by k_xu).
// hh (which 1,3): 16x16x32 frag (A-operand in k_lstm_fused).
__global__ void k_pack_all(const float* __restrict__ w0, u32x4* __restrict__ f0,
                           const float* __restrict__ w1, u32x4* __restrict__ f1,
                           const float* __restrict__ w2, u32x4* __restrict__ f2,
                           const float* __restrict__ w3, u32x4* __restrict__ f3) {
    int gt = blockIdx.x * 256 + threadIdx.x;     // 0..32767
    int which = gt >> 13;
    int tid  = gt & 8191;
    const float* wsrc = (which == 0) ? w0 : (which == 1) ? w1 : (which == 2) ? w2 : w3;
    u32x4* frag = (which == 0) ? f0 : (which == 1) ? f1 : (which == 2) ? f2 : f3;
    int lane = tid & 63;
    float v[8];
    int row;
    if ((which & 1) == 0) {
        int tile = (tid >> 6) & 15;
        int kst  = tid >> 10;
        row = tile * 32 + (lane & 31);
        int kbase = kst * 16 + (lane >> 5) * 8;
#pragma unroll
        for (int j = 0; j < 8; ++j) v[j] = wsrc[row * 128 + kbase + j];
    } else {
        int f  = tid >> 6;            // 0..127
        int ks = f & 3;
        int w8 = (f >> 2) & 7;
        int g  = f >> 5;
        row = g * 128 + w8 * 16 + (lane & 15);
        int kbase = ks * 32 + (lane >> 4) * 8;
#pragma unroll
        for (int j = 0; j < 8; ++j) v[j] = wsrc[row * 128 + kbase + j];
    }
    const float sc = ((row >> 7) == 2) ? TWO_LOG2E : LOG2E;
#pragma unroll
    for (int j = 0; j < 8; ++j) v[j] *= sc;
    u32x4 d;
    d.x = pack2bf16(v[0], v[1]);
    d.y = pack2bf16(v[2], v[3]);
    d.z = pack2bf16(v[4], v[5]);
    d.w = pack2bf16(v[6], v[7]);
    frag[tid] = d;
}

// Pack output-linear weights as A-frags over K=256 concat [Wself ; Wneigh].
// (UNSCALED - epilogue activations use natural units.)
__global__ void k_pack_out(const float* __restrict__ ws1, const float* __restrict__ wn1,
                           u32x4* __restrict__ f1,
                           const float* __restrict__ ws2, const float* __restrict__ wn2,
                           u32x4* __restrict__ f2) {
    int t = blockIdx.x * 256 + threadIdx.x;   // 0..6143
    int lane = t & 63;
    int row  = lane & 15;
    int kb   = (lane >> 4) * 8;
    float v[8];
    const float* ws; const float* wn; u32x4* dst; int p;
    if (t < 4096) { ws = ws1; wn = wn1; dst = f1; p = t; }
    else          { ws = ws2; wn = wn2; dst = f2; p = t - 4096; }
    int ks  = (p >> 6) & 7;
    int och = (p >> 9) * 16 + row;
    int kbase = ks * 32 + kb;
#pragma unroll
    for (int j = 0; j < 8; ++j) {
        int k = kbase + j;
        v[j] = (k < 128) ? ws[och * 128 + k] : wn[och * 128 + k - 128];
    }
    u32x4 d;
    d.x = pack2bf16(v[0], v[1]);
    d.y = pack2bf16(v[2], v[3]);
    d.z = pack2bf16(v[4], v[5]);
    d.w = pack2bf16(v[6], v[7]);
    dst[p] = d;
}

// ---------- kernel A: Xu = x @ W_ih^T + (b_ih+b_hh), gate-quad row store ----------
// biases pre-scaled to match the weight scaling (gate g x 2log2e, others x log2e).
__global__ __launch_bounds__(256, 2) void k_xu(
    const ushort* __restrict__ x,       // [N,128] bf16
    const u32x4*  __restrict__ wih,     // 8192 B-frags (32x32 layout, scaled)
    const float*  __restrict__ b_ih,    // [512]
    const float*  __restrict__ b_hh,    // [512]
    u32x2*        __restrict__ xu,      // [Nceil][128] u32x2 (1KB rows)
    int N)
{
    __shared__ u32x4 a_buf[16][66];

    const int tid   = threadIdx.x;
    const int lane  = tid & 63;
    const int w     = tid >> 6;
    const int mrow  = lane & 31;
    const int khalf = lane >> 5;
    const int node0 = blockIdx.x * 64;

    u32x4 wreg[8][4];
#pragma unroll
    for (int kst = 0; kst < 8; ++kst)
#pragma unroll
        for (int g = 0; g < 4; ++g)
            wreg[kst][g] = wih[(kst * 16 + g * 4 + w) * 64 + lane];

    float binit[4];
#pragma unroll
    for (int g = 0; g < 4; ++g) {
        int jj = g * 128 + w * 32 + mrow;
        binit[g] = (b_ih[jj] + b_hh[jj]) * ((g == 2) ? TWO_LOG2E : LOG2E);
    }

    {
        int m_st = tid >> 2, c4 = tid & 3;
        int gn = node0 + m_st; if (gn >= N) gn = N - 1;
        const u32x4* src = (const u32x4*)(x + (size_t)gn * IN);
#pragma unroll
        for (int q = 0; q < 4; ++q) {
            int kg = q * 4 + c4;
            a_buf[kg][m_st] = src[kg];
        }
    }
    __syncthreads();

    const int coff = w * 32 + mrow;
#pragma unroll 1
    for (int Mt = 0; Mt < 2; ++Mt) {
        f32x16 acc[4];
#pragma unroll
        for (int g = 0; g < 4; ++g)
#pragma unroll
            for (int r = 0; r < 16; ++r) acc[g][r] = binit[g];

#pragma unroll
        for (int kst = 0; kst < 8; ++kst) {
            bf16x8 a = __builtin_bit_cast(bf16x8, a_buf[kst * 2 + khalf][Mt * 32 + mrow]);
#pragma unroll
            for (int g = 0; g < 4; ++g)
                acc[g] = __builtin_amdgcn_mfma_f32_32x32x16_bf16(
                    a, __builtin_bit_cast(bf16x8, wreg[kst][g]), acc[g], 0, 0, 0);
        }

#pragma unroll
        for (int r = 0; r < 16; ++r) {
            int m = Mt * 32 + (r & 3) + 8 * (r >> 2) + 4 * khalf;
            u32x2 d;
            d.x = pack2bf16(acc[0][r], acc[1][r]);
            d.y = pack2bf16(acc[2][r], acc[3][r]);
            xu[(size_t)(node0 + m) * 128 + coff] = d;
        }
    }
}

// ---------- kernel B: recurrent LSTM (C^T) + fused output linear ----------
// wave w owns channels [w*16,w*16+16) of ALL 4 gates; C^T: row = channel
// (l4*4+q), col = node. Lane owns 4 ADJACENT channels of 1 node per tile ->
// shfl-free h pack. h LDS: [node][ch] bf16, row stride 272B (17x16B).
template <int NOUT, int ACT, typename OutT>
__global__ __launch_bounds__(512, 4) void k_lstm_fused(
    const u32x2*  __restrict__ xu,      // 1KB gate-quad rows (scaled units)
    const int*    __restrict__ nbr,     // [N,16]
    const u32x4*  __restrict__ whh,     // 128 frags (A-operand, scaled)
    const u32x4*  __restrict__ wout,    // epilogue A-frags (K=256 concat)
    const float*  __restrict__ bout,    // [NOUT]
    const ushort* __restrict__ x_in,    // [N,128] bf16 (self input)
    OutT*         __restrict__ out,     // [N,NOUT]
    int N)
{
    constexpr int HSTR = 272;                        // 17 x 16B, b128-aligned
    __shared__ alignas(16) char h_lds[2][32 * HSTR]; // 2 x 8.5KB
    __shared__ uint32_t idxs[DEG * 32];              // prescaled byte offsets

    const int tid  = threadIdx.x;
    const int lane = tid & 63;
    const int w    = tid >> 6;
    const int col  = lane & 15;
    const int l4   = lane >> 4;
    const int node0 = blockIdx.x * 32;

    {
        int m = tid & 31, t = tid >> 5;
        int gn = node0 + m; if (gn >= N) gn = N - 1;
        idxs[t * 32 + m] = (uint32_t)nbr[gn * DEG + t] << 10;
    }
    for (int i = tid; i < 32 * HSTR / 16; i += 512)
        ((u32x4*)h_lds[0])[i] = u32x4{0u, 0u, 0u, 0u};

    // W_hh A-frags: 64 regs
    u32x4 wreg[4][4];
#pragma unroll
    for (int g = 0; g < 4; ++g)
#pragma unroll
        for (int ks = 0; ks < 4; ++ks)
            wreg[g][ks] = whh[((g * 8 + w) * 4 + ks) * 64 + lane];

    float cst[8];
#pragma unroll
    for (int r = 0; r < 8; ++r) cst[r] = 0.0f;

    const char* xu_c = (const char*)xu;
    const uint32_t goff = (uint32_t)(w * 128 + l4 * 32);  // slice byte in xu row
    const int rd0 = col * HSTR + l4 * 16;                 // + ks*64 + mt*16*HSTR
    const int wr0 = col * HSTR + w * 32 + l4 * 8;         // + mt*16*HSTR

    __syncthreads();   // idxs + h(-1) zeros visible

    // prologue gather (step 0): 32B contiguous per (node, ch-quad)
    u32x4 vv[4];
    {
        const char* p0 = xu_c + idxs[col] + goff;
        const char* p1 = xu_c + idxs[16 + col] + goff;
        vv[0] = *(const u32x4*)(p0);
        vv[1] = *(const u32x4*)(p0 + 16);
        vv[2] = *(const u32x4*)(p1);
        vv[3] = *(const u32x4*)(p1 + 16);
    }

#pragma unroll 1
    for (int t = 0; t < DEG; ++t) {
        const char* hr = h_lds[t & 1];
        char*       hw = h_lds[(t + 1) & 1];

#pragma unroll
        for (int mt = 0; mt < 2; ++mt) {
            // ---- acc init: C^T element (ch = w*16+l4*4+q, node = mt*16+col)
            f32x4 acc[4];
#pragma unroll
            for (int q = 0; q < 4; ++q) {
                uint32_t px = vv[mt * 2 + (q >> 1)][(q & 1) * 2];
                uint32_t py = vv[mt * 2 + (q >> 1)][(q & 1) * 2 + 1];
                acc[0][q] = __uint_as_float(px << 16);
                acc[1][q] = __uint_as_float(px & 0xFFFF0000u);
                acc[2][q] = __uint_as_float(py << 16);
                acc[3][q] = __uint_as_float(py & 0xFFFF0000u);
            }

            // ---- prefetch next step once vv fully consumed
            if (mt == 1 && t + 1 < DEG) {
                const char* p0 = xu_c + idxs[(t + 1) * 32 + col] + goff;
                const char* p1 = xu_c + idxs[(t + 1) * 32 + 16 + col] + goff;
                vv[0] = *(const u32x4*)(p0);
                vv[1] = *(const u32x4*)(p0 + 16);
                vv[2] = *(const u32x4*)(p1);
                vv[3] = *(const u32x4*)(p1 + 16);
            }

            // ---- MFMA C^T: A = W_hh frags, B = h(t-1) from LDS
#pragma unroll
            for (int ks = 0; ks < 4; ++ks) {
                bf16x8 b = *(const bf16x8*)(hr + mt * 16 * HSTR + rd0 + ks * 64);
#pragma unroll
                for (int g = 0; g < 4; ++g)
                    acc[g] = __builtin_amdgcn_mfma_f32_16x16x32_bf16(
                        __builtin_bit_cast(bf16x8, wreg[g][ks]), b, acc[g], 0, 0, 0);
            }

            // ---- R16 cell (tight chains), exps are mul-free via prescale
            float hv[4];
#pragma unroll
            for (int q = 0; q < 4; ++q) {
                int r = mt * 4 + q;
                float iv = sig2(acc[0][q]);
                float fv = sig2(acc[1][q]);
                float gv = tanh2(acc[2][q]);
                float ov = sig2(acc[3][q]);
                float cv = __fmaf_rn(fv, cst[r], iv * gv);
                cst[r] = cv;
                hv[q] = ov * tanh2(cv * TWO_LOG2E);
            }
            u32x2 hp;
            hp.x = pack2bf16(hv[0], hv[1]);
            hp.y = pack2bf16(hv[2], hv[3]);
            *(u32x2*)(hw + mt * 16 * HSTR + wr0) = hp;
        }

        __syncthreads();   // h(t) visible; WAR-safe via dbuf (1 barrier/step)
    }

    // ---- fused output linear: out = act([x|h] @ [Ws;Wn]^T + b), C^T MFMA
    {
        const char* hf = h_lds[0];                 // h(15) parity: buf[16&1]
        constexpr int TILES = (NOUT == 128) ? 2 : 1;
        const int otile = (NOUT == 128) ? w : (w & 3);
        const int mtb   = (NOUT == 128) ? 0 : (w >> 2);
        const int och0  = otile * 16 + l4 * 4;
        const float4 bq = *(const float4*)(bout + och0);

#pragma unroll
        for (int mi = 0; mi < TILES; ++mi) {
            const int mt = mtb + mi;
            const int gn = node0 + mt * 16 + col;
            const int gx = (gn < N) ? gn : (N - 1);
            f32x4 acc = {bq.x, bq.y, bq.z, bq.w};
#pragma unroll
            for (int ks = 0; ks < 8; ++ks) {
                u32x4 af = wout[(otile * 8 + ks) * 64 + lane];
                bf16x8 bf_;
                if (ks < 4)
                    bf_ = *(const bf16x8*)((const char*)x_in + (size_t)gx * 256 +
                                           ks * 64 + l4 * 16);
                else
                    bf_ = *(const bf16x8*)(hf + mt * 16 * HSTR + col * HSTR +
                                           (ks - 4) * 64 + l4 * 16);
                acc = __builtin_amdgcn_mfma_f32_16x16x32_bf16(
                    __builtin_bit_cast(bf16x8, af), bf_, acc, 0, 0, 0);
            }
            if (gn < N) {
                float av[4];
#pragma unroll
                for (int q = 0; q < 4; ++q)
                    av[q] = (ACT == 0) ? fmaxf(acc[q], 0.0f) : fsigmoid(acc[q]);
                if constexpr (sizeof(OutT) == 2) {
                    u32x2 o;
                    o.x = pack2bf16(av[0], av[1]);
                    o.y = pack2bf16(av[2], av[3]);
                    *(u32x2*)((ushort*)out + (size_t)gn * NOUT + och0) = o;
                } else {
                    f32x4 o = {av[0], av[1], av[2], av[3]};
                    *(f32x4*)((float*)out + (size_t)gn * NOUT + och0) = o;
                }
            }
        }
    }
}

extern "C" void kernel_launch(void* const* d_in, const int* in_sizes, int n_in,
                              void* d_out, int out_size, void* d_ws, size_t ws_size,
                              hipStream_t stream)
{
    const float* feats    = (const float*)d_in[0];
    const int*   nbr      = (const int*)  d_in[1];
    const float* w_ih1    = (const float*)d_in[2];
    const float* w_hh1    = (const float*)d_in[3];
    const float* b_ih1    = (const float*)d_in[4];
    const float* b_hh1    = (const float*)d_in[5];
    const float* w_self1  = (const float*)d_in[6];
    const float* w_neigh1 = (const float*)d_in[7];
    const float* b1       = (const float*)d_in[8];
    const float* w_ih2    = (const float*)d_in[9];
    const float* w_hh2    = (const float*)d_in[10];
    const float* b_ih2    = (const float*)d_in[11];
    const float* b_hh2    = (const float*)d_in[12];
    const float* w_self2  = (const float*)d_in[13];
    const float* w_neigh2 = (const float*)d_in[14];
    const float* b2       = (const float*)d_in[15];
    float* out = (float*)d_out;

    const int N = in_sizes[0] / IN;   // 50000
    const long long Nceil = (N + 63) & ~63LL;

    char* ws = (char*)d_ws;
    size_t off = 0;
    auto alloc = [&](size_t bytes) -> void* {
        void* p = (void*)(ws + off);
        off += (bytes + 255) & ~(size_t)255;
        return p;
    };
    u32x4*  wfrag_ih1 = (u32x4*)alloc(8192 * 16);
    u32x4*  wfrag_hh1 = (u32x4*)alloc(8192 * 16);
    u32x4*  wfrag_ih2 = (u32x4*)alloc(8192 * 16);
    u32x4*  wfrag_hh2 = (u32x4*)alloc(8192 * 16);
    u32x4*  wofrag1   = (u32x4*)alloc(4096 * 16);   // 64KB epilogue A-frags L1
    u32x4*  wofrag2   = (u32x4*)alloc(2048 * 16);   // 32KB epilogue A-frags L2
    ushort* feats_bf  = (ushort*)alloc((size_t)N * 128 * 2);
    ushort* out1      = (ushort*)alloc((size_t)N * 128 * 2);
    u32x2*  xu_buf    = (u32x2*)alloc((size_t)Nceil * 128 * 8);   // 51.25MB

    // prep
    k_pack_all<<<dim3(128), dim3(256), 0, stream>>>(w_ih1, wfrag_ih1, w_hh1, wfrag_hh1,
                                                    w_ih2, wfrag_ih2, w_hh2, wfrag_hh2);
    k_pack_out<<<dim3(24), dim3(256), 0, stream>>>(w_self1, w_neigh1, wofrag1,
                                                   w_self2, w_neigh2, wofrag2);
    k_cast_bf16<<<dim3((N * 128 / 4 + 255) / 256), dim3(256), 0, stream>>>(feats, feats_bf, N * 128);

    const int nblk64 = (int)(Nceil / 64);
    const int nblk32 = (N + 31) / 32;

    // layer 1
    k_xu<<<dim3(nblk64), dim3(256), 0, stream>>>(feats_bf, wfrag_ih1, b_ih1, b_hh1, xu_buf, N);
    k_lstm_fused<128, 0, ushort><<<dim3(nblk32), dim3(512), 0, stream>>>(
        xu_buf, nbr, wfrag_hh1, wofrag1, b1, feats_bf, out1, N);

    // layer 2
    k_xu<<<dim3(nblk64), dim3(256), 0, stream>>>(out1, wfrag_ih2, b_ih2, b_hh2, xu_buf, N);
    k_lstm_fused<64, 1, float><<<dim3(nblk32), dim3(512), 0, stream>>>(
        xu_buf, nbr, wfrag_hh2, wofrag2, b2, out1, out, N);
}

// Round 10
// 513.043 us; speedup vs baseline: 1.3153x; 1.0072x over previous
//
#include <hip/hip_runtime.h>
#include <cstdint>
#include <cstddef>

// SAGE-LSTM R21: R20 + h-stage-only trans fold (10 -> 9 trans/element).
// R20 validated: exp2 prescale, 28MB WRITE_SIZE (no spill), 209us/dispatch,
// VALU issue 117us (model-exact). Remaining structure: trans floor 104us +
// ~92us serial-recurrence stalls.
// R21: fold ONLY the output stage: sig(o)*tanh(c) = (1-Ec)*rcp((1+Eo)(1+Ec)).
// R18 proved this fold numerically (passed, absmax 0.0039); R18's spill is
// attributed to the OTHER fold (ig: Ei,Eg,(1-Eg) co-live across the pending
// c-chain). Here only Eo's liveness extends, by 2 instructions. i,f,g keep
// R20's tight exp2->rcp chains. 9 trans/elem; -1 rcp = -16 issue-cyc/elem.

constexpr int IN  = 128;
constexpr int DEG = 16;
#define LOG2E       1.4426950408889634f
#define TWO_LOG2E   2.8853900817779268f
#define NEG2_LOG2E -2.8853900817779268f

typedef short bf16x8 __attribute__((ext_vector_type(8)));
typedef float f32x4  __attribute__((ext_vector_type(4)));
typedef float f32x16 __attribute__((ext_vector_type(16)));
typedef unsigned int u32x4 __attribute__((ext_vector_type(4)));
typedef unsigned int u32x2 __attribute__((ext_vector_type(2)));

__device__ __forceinline__ float fsigmoid(float x) {   // unscaled input
    float e = __expf(-x);
    return __builtin_amdgcn_rcpf(1.0f + e);
}
// sigma(x) with y = x*log2e pre-scaled into the weights
__device__ __forceinline__ float sig2(float y) {
    float e = __builtin_amdgcn_exp2f(-y);
    return __builtin_amdgcn_rcpf(1.0f + e);
}
// tanh(x) with y = 2x*log2e pre-scaled
__device__ __forceinline__ float tanh2(float y) {
    float e = __builtin_amdgcn_exp2f(-y);
    return __fmaf_rn(2.0f, __builtin_amdgcn_rcpf(1.0f + e), -1.0f);
}
__device__ __forceinline__ uint32_t pack2bf16(float a, float b) {
    uint32_t ua = __float_as_uint(a) + 0x8000u;
    uint32_t ub = __float_as_uint(b) + 0x8000u;
    return (ua >> 16) | (ub & 0xFFFF0000u);
}

// ---------- prep kernels ----------

__global__ void k_cast_bf16(const float* __restrict__ src, ushort* __restrict__ dst, int n) {
    int i = (blockIdx.x * blockDim.x + threadIdx.x) * 4;
    if (i + 3 < n) {
        float4 v = *(const float4*)(src + i);
        uint2 d; d.x = pack2bf16(v.x, v.y); d.y = pack2bf16(v.z, v.w);
        *(uint2*)(dst + i) = d;
    } else {
        for (int k = i; k < n; ++k)
            dst[k] = (ushort)((__float_as_uint(src[k]) + 0x8000u) >> 16);
    }
}

// Pack all 4 [512 x 128] gate weights into MFMA fragment order, PRE-SCALED:
// gate rows i,f,o (rows 0..255, 384..511) x log2e; gate g (256..383) x 2log2e.
// ih (which 0,2): 32x32x16 B-frag (consumed by k_xu).
// hh (which 1,3): 16x16x32 frag (A-operand in k_lstm_fused).
__global__ void k_pack_all(const float* __restrict__ w0, u32x4* __restrict__ f0,
                           const float* __restrict__ w1, u32x4* __restrict__ f1,
                           const float* __restrict__ w2, u32x4* __restrict__ f2,
                           const float* __restrict__ w3, u32x4* __restrict__ f3) {
    int gt = blockIdx.x * 256 + threadIdx.x;     // 0..32767
    int which = gt >> 13;
    int tid  = gt & 8191;
    const float* wsrc = (which == 0) ? w0 : (which == 1) ? w1 : (which == 2) ? w2 : w3;
    u32x4* frag = (which == 0) ? f0 : (which == 1) ? f1 : (which == 2) ? f2 : f3;
    int lane = tid & 63;
    float v[8];
    int row;
    if ((which & 1) == 0) {
        int tile = (tid >> 6) & 15;
        int kst  = tid >> 10;
        row = tile * 32 + (lane & 31);
        int kbase = kst * 16 + (lane >> 5) * 8;
#pragma unroll
        for (int j = 0; j < 8; ++j) v[j] = wsrc[row * 128 + kbase + j];
    } else {
        int f  = tid >> 6;            // 0..127
        int ks = f & 3;
        int w8 = (f >> 2) & 7;
        int g  = f >> 5;
        row = g * 128 + w8 * 16 + (lane & 15);
        int kbase = ks * 32 + (lane >> 4) * 8;
#pragma unroll
        for (int j = 0; j < 8; ++j) v[j] = wsrc[row * 128 + kbase + j];
    }
    const float sc = ((row >> 7) == 2) ? TWO_LOG2E : LOG2E;
#pragma unroll
    for (int j = 0; j < 8; ++j) v[j] *= sc;
    u32x4 d;
    d.x = pack2bf16(v[0], v[1]);
    d.y = pack2bf16(v[2], v[3]);
    d.z = pack2bf16(v[4], v[5]);
    d.w = pack2bf16(v[6], v[7]);
    frag[tid] = d;
}

// Pack output-linear weights as A-frags over K=256 concat [Wself ; Wneigh].
// (UNSCALED - epilogue activations use natural units.)
__global__ void k_pack_out(const float* __restrict__ ws1, const float* __restrict__ wn1,
                           u32x4* __restrict__ f1,
                           const float* __restrict__ ws2, const float* __restrict__ wn2,
                           u32x4* __restrict__ f2) {
    int t = blockIdx.x * 256 + threadIdx.x;   // 0..6143
    int lane = t & 63;
    int row  = lane & 15;
    int kb   = (lane >> 4) * 8;
    float v[8];
    const float* ws; const float* wn; u32x4* dst; int p;
    if (t < 4096) { ws = ws1; wn = wn1; dst = f1; p = t; }
    else          { ws = ws2; wn = wn2; dst = f2; p = t - 4096; }
    int ks  = (p >> 6) & 7;
    int och = (p >> 9) * 16 + row;
    int kbase = ks * 32 + kb;
#pragma unroll
    for (int j = 0; j < 8; ++j) {
        int k = kbase + j;
        v[j] = (k < 128) ? ws[och * 128 + k] : wn[och * 128 + k - 128];
    }
    u32x4 d;
    d.x = pack2bf16(v[0], v[1]);
    d.y = pack2bf16(v[2], v[3]);
    d.z = pack2bf16(v[4], v[5]);
    d.w = pack2bf16(v[6], v[7]);
    dst[p] = d;
}

// ---------- kernel A: Xu = x @ W_ih^T + (b_ih+b_hh), gate-quad row store ----------
// biases pre-scaled to match the weight scaling (gate g x 2log2e, others x log2e).
__global__ __launch_bounds__(256, 2) void k_xu(
    const ushort* __restrict__ x,       // [N,128] bf16
    const u32x4*  __restrict__ wih,     // 8192 B-frags (32x32 layout, scaled)
    const float*  __restrict__ b_ih,    // [512]
    const float*  __restrict__ b_hh,    // [512]
    u32x2*        __restrict__ xu,      // [Nceil][128] u32x2 (1KB rows)
    int N)
{
    __shared__ u32x4 a_buf[16][66];

    const int tid   = threadIdx.x;
    const int lane  = tid & 63;
    const int w     = tid >> 6;
    const int mrow  = lane & 31;
    const int khalf = lane >> 5;
    const int node0 = blockIdx.x * 64;

    u32x4 wreg[8][4];
#pragma unroll
    for (int kst = 0; kst < 8; ++kst)
#pragma unroll
        for (int g = 0; g < 4; ++g)
            wreg[kst][g] = wih[(kst * 16 + g * 4 + w) * 64 + lane];

    float binit[4];
#pragma unroll
    for (int g = 0; g < 4; ++g) {
        int jj = g * 128 + w * 32 + mrow;
        binit[g] = (b_ih[jj] + b_hh[jj]) * ((g == 2) ? TWO_LOG2E : LOG2E);
    }

    {
        int m_st = tid >> 2, c4 = tid & 3;
        int gn = node0 + m_st; if (gn >= N) gn = N - 1;
        const u32x4* src = (const u32x4*)(x + (size_t)gn * IN);
#pragma unroll
        for (int q = 0; q < 4; ++q) {
            int kg = q * 4 + c4;
            a_buf[kg][m_st] = src[kg];
        }
    }
    __syncthreads();

    const int coff = w * 32 + mrow;
#pragma unroll 1
    for (int Mt = 0; Mt < 2; ++Mt) {
        f32x16 acc[4];
#pragma unroll
        for (int g = 0; g < 4; ++g)
#pragma unroll
            for (int r = 0; r < 16; ++r) acc[g][r] = binit[g];

#pragma unroll
        for (int kst = 0; kst < 8; ++kst) {
            bf16x8 a = __builtin_bit_cast(bf16x8, a_buf[kst * 2 + khalf][Mt * 32 + mrow]);
#pragma unroll
            for (int g = 0; g < 4; ++g)
                acc[g] = __builtin_amdgcn_mfma_f32_32x32x16_bf16(
                    a, __builtin_bit_cast(bf16x8, wreg[kst][g]), acc[g], 0, 0, 0);
        }

#pragma unroll
        for (int r = 0; r < 16; ++r) {
            int m = Mt * 32 + (r & 3) + 8 * (r >> 2) + 4 * khalf;
            u32x2 d;
            d.x = pack2bf16(acc[0][r], acc[1][r]);
            d.y = pack2bf16(acc[2][r], acc[3][r]);
            xu[(size_t)(node0 + m) * 128 + coff] = d;
        }
    }
}

// ---------- kernel B: recurrent LSTM (C^T) + fused output linear ----------
// wave w owns channels [w*16,w*16+16) of ALL 4 gates; C^T: row = channel
// (l4*4+q), col = node. Lane owns 4 ADJACENT channels of 1 node per tile ->
// shfl-free h pack. h LDS: [node][ch] bf16, row stride 272B (17x16B).
template <int NOUT, int ACT, typename OutT>
__global__ __launch_bounds__(512, 4) void k_lstm_fused(
    const u32x2*  __restrict__ xu,      // 1KB gate-quad rows (scaled units)
    const int*    __restrict__ nbr,     // [N,16]
    const u32x4*  __restrict__ whh,     // 128 frags (A-operand, scaled)
    const u32x4*  __restrict__ wout,    // epilogue A-frags (K=256 concat)
    const float*  __restrict__ bout,    // [NOUT]
    const ushort* __restrict__ x_in,    // [N,128] bf16 (self input)
    OutT*         __restrict__ out,     // [N,NOUT]
    int N)
{
    constexpr int HSTR = 272;                        // 17 x 16B, b128-aligned
    __shared__ alignas(16) char h_lds[2][32 * HSTR]; // 2 x 8.5KB
    __shared__ uint32_t idxs[DEG * 32];              // prescaled byte offsets

    const int tid  = threadIdx.x;
    const int lane = tid & 63;
    const int w    = tid >> 6;
    const int col  = lane & 15;
    const int l4   = lane >> 4;
    const int node0 = blockIdx.x * 32;

    {
        int m = tid & 31, t = tid >> 5;
        int gn = node0 + m; if (gn >= N) gn = N - 1;
        idxs[t * 32 + m] = (uint32_t)nbr[gn * DEG + t] << 10;
    }
    for (int i = tid; i < 32 * HSTR / 16; i += 512)
        ((u32x4*)h_lds[0])[i] = u32x4{0u, 0u, 0u, 0u};

    // W_hh A-frags: 64 regs
    u32x4 wreg[4][4];
#pragma unroll
    for (int g = 0; g < 4; ++g)
#pragma unroll
        for (int ks = 0; ks < 4; ++ks)
            wreg[g][ks] = whh[((g * 8 + w) * 4 + ks) * 64 + lane];

    float cst[8];
#pragma unroll
    for (int r = 0; r < 8; ++r) cst[r] = 0.0f;

    const char* xu_c = (const char*)xu;
    const uint32_t goff = (uint32_t)(w * 128 + l4 * 32);  // slice byte in xu row
    const int rd0 = col * HSTR + l4 * 16;                 // + ks*64 + mt*16*HSTR
    const int wr0 = col * HSTR + w * 32 + l4 * 8;         // + mt*16*HSTR

    __syncthreads();   // idxs + h(-1) zeros visible

    // prologue gather (step 0): 32B contiguous per (node, ch-quad)
    u32x4 vv[4];
    {
        const char* p0 = xu_c + idxs[col] + goff;
        const char* p1 = xu_c + idxs[16 + col] + goff;
        vv[0] = *(const u32x4*)(p0);
        vv[1] = *(const u32x4*)(p0 + 16);
        vv[2] = *(const u32x4*)(p1);
        vv[3] = *(const u32x4*)(p1 + 16);
    }

#pragma unroll 1
    for (int t = 0; t < DEG; ++t) {
        const char* hr = h_lds[t & 1];
        char*       hw = h_lds[(t + 1) & 1];

#pragma unroll
        for (int mt = 0; mt < 2; ++mt) {
            // ---- acc init: C^T element (ch = w*16+l4*4+q, node = mt*16+col)
            f32x4 acc[4];
#pragma unroll
            for (int q = 0; q < 4; ++q) {
                uint32_t px = vv[mt * 2 + (q >> 1)][(q & 1) * 2];
                uint32_t py = vv[mt * 2 + (q >> 1)][(q & 1) * 2 + 1];
                acc[0][q] = __uint_as_float(px << 16);
                acc[1][q] = __uint_as_float(px & 0xFFFF0000u);
                acc[2][q] = __uint_as_float(py << 16);
                acc[3][q] = __uint_as_float(py & 0xFFFF0000u);
            }

            // ---- prefetch next step once vv fully consumed
            if (mt == 1 && t + 1 < DEG) {
                const char* p0 = xu_c + idxs[(t + 1) * 32 + col] + goff;
                const char* p1 = xu_c + idxs[(t + 1) * 32 + 16 + col] + goff;
                vv[0] = *(const u32x4*)(p0);
                vv[1] = *(const u32x4*)(p0 + 16);
                vv[2] = *(const u32x4*)(p1);
                vv[3] = *(const u32x4*)(p1 + 16);
            }

            // ---- MFMA C^T: A = W_hh frags, B = h(t-1) from LDS
#pragma unroll
            for (int ks = 0; ks < 4; ++ks) {
                bf16x8 b = *(const bf16x8*)(hr + mt * 16 * HSTR + rd0 + ks * 64);
#pragma unroll
                for (int g = 0; g < 4; ++g)
                    acc[g] = __builtin_amdgcn_mfma_f32_16x16x32_bf16(
                        __builtin_bit_cast(bf16x8, wreg[g][ks]), b, acc[g], 0, 0, 0);
            }

            // ---- cell: i,f,g tight chains + folded output stage (9 trans)
            float hv[4];
#pragma unroll
            for (int q = 0; q < 4; ++q) {
                int r = mt * 4 + q;
                float iv = sig2(acc[0][q]);
                float fv = sig2(acc[1][q]);
                float gv = tanh2(acc[2][q]);
                float cv = __fmaf_rn(fv, cst[r], iv * gv);
                cst[r] = cv;
                // sig(o)*tanh(c) = (1-Ec) * rcp((1+Eo)(1+Ec))
                float Eo = __builtin_amdgcn_exp2f(-acc[3][q]);
                float Ec = __builtin_amdgcn_exp2f(cv * NEG2_LOG2E);
                hv[q] = (1.0f - Ec) *
                        __builtin_amdgcn_rcpf((1.0f + Eo) * (1.0f + Ec));
            }
            u32x2 hp;
            hp.x = pack2bf16(hv[0], hv[1]);
            hp.y = pack2bf16(hv[2], hv[3]);
            *(u32x2*)(hw + mt * 16 * HSTR + wr0) = hp;
        }

        __syncthreads();   // h(t) visible; WAR-safe via dbuf (1 barrier/step)
    }

    // ---- fused output linear: out = act([x|h] @ [Ws;Wn]^T + b), C^T MFMA
    {
        const char* hf = h_lds[0];                 // h(15) parity: buf[16&1]
        constexpr int TILES = (NOUT == 128) ? 2 : 1;
        const int otile = (NOUT == 128) ? w : (w & 3);
        const int mtb   = (NOUT == 128) ? 0 : (w >> 2);
        const int och0  = otile * 16 + l4 * 4;
        const float4 bq = *(const float4*)(bout + och0);

#pragma unroll
        for (int mi = 0; mi < TILES; ++mi) {
            const int mt = mtb + mi;
            const int gn = node0 + mt * 16 + col;
            const int gx = (gn < N) ? gn : (N - 1);
            f32x4 acc = {bq.x, bq.y, bq.z, bq.w};
#pragma unroll
            for (int ks = 0; ks < 8; ++ks) {
                u32x4 af = wout[(otile * 8 + ks) * 64 + lane];
                bf16x8 bf_;
                if (ks < 4)
                    bf_ = *(const bf16x8*)((const char*)x_in + (size_t)gx * 256 +
                                           ks * 64 + l4 * 16);
                else
                    bf_ = *(const bf16x8*)(hf + mt * 16 * HSTR + col * HSTR +
                                           (ks - 4) * 64 + l4 * 16);
                acc = __builtin_amdgcn_mfma_f32_16x16x32_bf16(
                    __builtin_bit_cast(bf16x8, af), bf_, acc, 0, 0, 0);
            }
            if (gn < N) {
                float av[4];
#pragma unroll
                for (int q = 0; q < 4; ++q)
                    av[q] = (ACT == 0) ? fmaxf(acc[q], 0.0f) : fsigmoid(acc[q]);
                if constexpr (sizeof(OutT) == 2) {
                    u32x2 o;
                    o.x = pack2bf16(av[0], av[1]);
                    o.y = pack2bf16(av[2], av[3]);
                    *(u32x2*)((ushort*)out + (size_t)gn * NOUT + och0) = o;
                } else {
                    f32x4 o = {av[0], av[1], av[2], av[3]};
                    *(f32x4*)((float*)out + (size_t)gn * NOUT + och0) = o;
                }
            }
        }
    }
}

extern "C" void kernel_launch(void* const* d_in, const int* in_sizes, int n_in,
                              void* d_out, int out_size, void* d_ws, size_t ws_size,
                              hipStream_t stream)
{
    const float* feats    = (const float*)d_in[0];
    const int*   nbr      = (const int*)  d_in[1];
    const float* w_ih1    = (const float*)d_in[2];
    const float* w_hh1    = (const float*)d_in[3];
    const float* b_ih1    = (const float*)d_in[4];
    const float* b_hh1    = (const float*)d_in[5];
    const float* w_self1  = (const float*)d_in[6];
    const float* w_neigh1 = (const float*)d_in[7];
    const float* b1       = (const float*)d_in[8];
    const float* w_ih2    = (const float*)d_in[9];
    const float* w_hh2    = (const float*)d_in[10];
    const float* b_ih2    = (const float*)d_in[11];
    const float* b_hh2    = (const float*)d_in[12];
    const float* w_self2  = (const float*)d_in[13];
    const float* w_neigh2 = (const float*)d_in[14];
    const float* b2       = (const float*)d_in[15];
    float* out = (float*)d_out;

    const int N = in_sizes[0] / IN;   // 50000
    const long long Nceil = (N + 63) & ~63LL;

    char* ws = (char*)d_ws;
    size_t off = 0;
    auto alloc = [&](size_t bytes) -> void* {
        void* p = (void*)(ws + off);
        off += (bytes + 255) & ~(size_t)255;
        return p;
    };
    u32x4*  wfrag_ih1 = (u32x4*)alloc(8192 * 16);
    u32x4*  wfrag_hh1 = (u32x4*)alloc(8192 * 16);
    u32x4*  wfrag_ih2 = (u32x4*)alloc(8192 * 16);
    u32x4*  wfrag_hh2 = (u32x4*)alloc(8192 * 16);
    u32x4*  wofrag1   = (u32x4*)alloc(4096 * 16);   // 64KB epilogue A-frags L1
    u32x4*  wofrag2   = (u32x4*)alloc(2048 * 16);   // 32KB epilogue A-frags L2
    ushort* feats_bf  = (ushort*)alloc((size_t)N * 128 * 2);
    ushort* out1      = (ushort*)alloc((size_t)N * 128 * 2);
    u32x2*  xu_buf    = (u32x2*)alloc((size_t)Nceil * 128 * 8);   // 51.25MB

    // prep
    k_pack_all<<<dim3(128), dim3(256), 0, stream>>>(w_ih1, wfrag_ih1, w_hh1, wfrag_hh1,
                                                    w_ih2, wfrag_ih2, w_hh2, wfrag_hh2);
    k_pack_out<<<dim3(24), dim3(256), 0, stream>>>(w_self1, w_neigh1, wofrag1,
                                                   w_self2, w_neigh2, wofrag2);
    k_cast_bf16<<<dim3((N * 128 / 4 + 255) / 256), dim3(256), 0, stream>>>(feats, feats_bf, N * 128);

    const int nblk64 = (int)(Nceil / 64);
    const int nblk32 = (N + 31) / 32;

    // layer 1
    k_xu<<<dim3(nblk64), dim3(256), 0, stream>>>(feats_bf, wfrag_ih1, b_ih1, b_hh1, xu_buf, N);
    k_lstm_fused<128, 0, ushort><<<dim3(nblk32), dim3(512), 0, stream>>>(
        xu_buf, nbr, wfrag_hh1, wofrag1, b1, feats_bf, out1, N);

    // layer 2
    k_xu<<<dim3(nblk64), dim3(256), 0, stream>>>(out1, wfrag_ih2, b_ih2, b_hh2, xu_buf, N);
    k_lstm_fused<64, 1, float><<<dim3(nblk32), dim3(512), 0, stream>>>(
        xu_buf, nbr, wfrag_hh2, wofrag2, b2, out1, out, N);
}

// Round 11
// 497.795 us; speedup vs baseline: 1.3556x; 1.0306x over previous
//
#include <hip/hip_runtime.h>
#include <cstdint>
#include <cstddef>

// SAGE-LSTM R22: BN 32->16 node-tiles to halve grid-tail quantization.
// R21 post-mortem: VALU-issue cuts now convert at ~25% to time -> stall-bound.
// Tail theory (two counters agree): 1563 blocks / 512 slots (2 blk/CU @(512,4))
// = 3.05 rounds -> 4 actual = 24% tail (~49us); predicted avg occupancy 38% vs
// measured 36.5%. R22: BN=16 -> 3125 blocks (50000/16 exact) = 6.10 rounds ->
// 7 actual = 12.8% tail. Kernel simplifies (no mt loop, cst 8->4, vv 4->2);
// register pressure strictly decreases. Cost: per-block fixed overhead
// amortized over half the nodes (~+5%); NOUT=64 epilogue uses 4 of 8 waves.

constexpr int IN  = 128;
constexpr int DEG = 16;
#define LOG2E       1.4426950408889634f
#define TWO_LOG2E   2.8853900817779268f
#define NEG2_LOG2E -2.8853900817779268f

typedef short bf16x8 __attribute__((ext_vector_type(8)));
typedef float f32x4  __attribute__((ext_vector_type(4)));
typedef float f32x16 __attribute__((ext_vector_type(16)));
typedef unsigned int u32x4 __attribute__((ext_vector_type(4)));
typedef unsigned int u32x2 __attribute__((ext_vector_type(2)));

__device__ __forceinline__ float fsigmoid(float x) {   // unscaled input
    float e = __expf(-x);
    return __builtin_amdgcn_rcpf(1.0f + e);
}
// sigma(x) with y = x*log2e pre-scaled into the weights
__device__ __forceinline__ float sig2(float y) {
    float e = __builtin_amdgcn_exp2f(-y);
    return __builtin_amdgcn_rcpf(1.0f + e);
}
// tanh(x) with y = 2x*log2e pre-scaled
__device__ __forceinline__ float tanh2(float y) {
    float e = __builtin_amdgcn_exp2f(-y);
    return __fmaf_rn(2.0f, __builtin_amdgcn_rcpf(1.0f + e), -1.0f);
}
__device__ __forceinline__ uint32_t pack2bf16(float a, float b) {
    uint32_t ua = __float_as_uint(a) + 0x8000u;
    uint32_t ub = __float_as_uint(b) + 0x8000u;
    return (ua >> 16) | (ub & 0xFFFF0000u);
}

// ---------- prep kernels ----------

__global__ void k_cast_bf16(const float* __restrict__ src, ushort* __restrict__ dst, int n) {
    int i = (blockIdx.x * blockDim.x + threadIdx.x) * 4;
    if (i + 3 < n) {
        float4 v = *(const float4*)(src + i);
        uint2 d; d.x = pack2bf16(v.x, v.y); d.y = pack2bf16(v.z, v.w);
        *(uint2*)(dst + i) = d;
    } else {
        for (int k = i; k < n; ++k)
            dst[k] = (ushort)((__float_as_uint(src[k]) + 0x8000u) >> 16);
    }
}

// Pack all 4 [512 x 128] gate weights into MFMA fragment order, PRE-SCALED:
// gate rows i,f,o (rows 0..255, 384..511) x log2e; gate g (256..383) x 2log2e.
// ih (which 0,2): 32x32x16 B-frag (consumed by k_xu).
// hh (which 1,3): 16x16x32 frag (A-operand in k_lstm_fused).
__global__ void k_pack_all(const float* __restrict__ w0, u32x4* __restrict__ f0,
                           const float* __restrict__ w1, u32x4* __restrict__ f1,
                           const float* __restrict__ w2, u32x4* __restrict__ f2,
                           const float* __restrict__ w3, u32x4* __restrict__ f3) {
    int gt = blockIdx.x * 256 + threadIdx.x;     // 0..32767
    int which = gt >> 13;
    int tid  = gt & 8191;
    const float* wsrc = (which == 0) ? w0 : (which == 1) ? w1 : (which == 2) ? w2 : w3;
    u32x4* frag = (which == 0) ? f0 : (which == 1) ? f1 : (which == 2) ? f2 : f3;
    int lane = tid & 63;
    float v[8];
    int row;
    if ((which & 1) == 0) {
        int tile = (tid >> 6) & 15;
        int kst  = tid >> 10;
        row = tile * 32 + (lane & 31);
        int kbase = kst * 16 + (lane >> 5) * 8;
#pragma unroll
        for (int j = 0; j < 8; ++j) v[j] = wsrc[row * 128 + kbase + j];
    } else {
        int f  = tid >> 6;            // 0..127
        int ks = f & 3;
        int w8 = (f >> 2) & 7;
        int g  = f >> 5;
        row = g * 128 + w8 * 16 + (lane & 15);
        int kbase = ks * 32 + (lane >> 4) * 8;
#pragma unroll
        for (int j = 0; j < 8; ++j) v[j] = wsrc[row * 128 + kbase + j];
    }
    const float sc = ((row >> 7) == 2) ? TWO_LOG2E : LOG2E;
#pragma unroll
    for (int j = 0; j < 8; ++j) v[j] *= sc;
    u32x4 d;
    d.x = pack2bf16(v[0], v[1]);
    d.y = pack2bf16(v[2], v[3]);
    d.z = pack2bf16(v[4], v[5]);
    d.w = pack2bf16(v[6], v[7]);
    frag[tid] = d;
}

// Pack output-linear weights as A-frags over K=256 concat [Wself ; Wneigh].
// (UNSCALED - epilogue activations use natural units.)
__global__ void k_pack_out(const float* __restrict__ ws1, const float* __restrict__ wn1,
                           u32x4* __restrict__ f1,
                           const float* __restrict__ ws2, const float* __restrict__ wn2,
                           u32x4* __restrict__ f2) {
    int t = blockIdx.x * 256 + threadIdx.x;   // 0..6143
    int lane = t & 63;
    int row  = lane & 15;
    int kb   = (lane >> 4) * 8;
    float v[8];
    const float* ws; const float* wn; u32x4* dst; int p;
    if (t < 4096) { ws = ws1; wn = wn1; dst = f1; p = t; }
    else          { ws = ws2; wn = wn2; dst = f2; p = t - 4096; }
    int ks  = (p >> 6) & 7;
    int och = (p >> 9) * 16 + row;
    int kbase = ks * 32 + kb;
#pragma unroll
    for (int j = 0; j < 8; ++j) {
        int k = kbase + j;
        v[j] = (k < 128) ? ws[och * 128 + k] : wn[och * 128 + k - 128];
    }
    u32x4 d;
    d.x = pack2bf16(v[0], v[1]);
    d.y = pack2bf16(v[2], v[3]);
    d.z = pack2bf16(v[4], v[5]);
    d.w = pack2bf16(v[6], v[7]);
    dst[p] = d;
}

// ---------- kernel A: Xu = x @ W_ih^T + (b_ih+b_hh), gate-quad row store ----------
// biases pre-scaled to match the weight scaling (gate g x 2log2e, others x log2e).
__global__ __launch_bounds__(256, 2) void k_xu(
    const ushort* __restrict__ x,       // [N,128] bf16
    const u32x4*  __restrict__ wih,     // 8192 B-frags (32x32 layout, scaled)
    const float*  __restrict__ b_ih,    // [512]
    const float*  __restrict__ b_hh,    // [512]
    u32x2*        __restrict__ xu,      // [Nceil][128] u32x2 (1KB rows)
    int N)
{
    __shared__ u32x4 a_buf[16][66];

    const int tid   = threadIdx.x;
    const int lane  = tid & 63;
    const int w     = tid >> 6;
    const int mrow  = lane & 31;
    const int khalf = lane >> 5;
    const int node0 = blockIdx.x * 64;

    u32x4 wreg[8][4];
#pragma unroll
    for (int kst = 0; kst < 8; ++kst)
#pragma unroll
        for (int g = 0; g < 4; ++g)
            wreg[kst][g] = wih[(kst * 16 + g * 4 + w) * 64 + lane];

    float binit[4];
#pragma unroll
    for (int g = 0; g < 4; ++g) {
        int jj = g * 128 + w * 32 + mrow;
        binit[g] = (b_ih[jj] + b_hh[jj]) * ((g == 2) ? TWO_LOG2E : LOG2E);
    }

    {
        int m_st = tid >> 2, c4 = tid & 3;
        int gn = node0 + m_st; if (gn >= N) gn = N - 1;
        const u32x4* src = (const u32x4*)(x + (size_t)gn * IN);
#pragma unroll
        for (int q = 0; q < 4; ++q) {
            int kg = q * 4 + c4;
            a_buf[kg][m_st] = src[kg];
        }
    }
    __syncthreads();

    const int coff = w * 32 + mrow;
#pragma unroll 1
    for (int Mt = 0; Mt < 2; ++Mt) {
        f32x16 acc[4];
#pragma unroll
        for (int g = 0; g < 4; ++g)
#pragma unroll
            for (int r = 0; r < 16; ++r) acc[g][r] = binit[g];

#pragma unroll
        for (int kst = 0; kst < 8; ++kst) {
            bf16x8 a = __builtin_bit_cast(bf16x8, a_buf[kst * 2 + khalf][Mt * 32 + mrow]);
#pragma unroll
            for (int g = 0; g < 4; ++g)
                acc[g] = __builtin_amdgcn_mfma_f32_32x32x16_bf16(
                    a, __builtin_bit_cast(bf16x8, wreg[kst][g]), acc[g], 0, 0, 0);
        }

#pragma unroll
        for (int r = 0; r < 16; ++r) {
            int m = Mt * 32 + (r & 3) + 8 * (r >> 2) + 4 * khalf;
            u32x2 d;
            d.x = pack2bf16(acc[0][r], acc[1][r]);
            d.y = pack2bf16(acc[2][r], acc[3][r]);
            xu[(size_t)(node0 + m) * 128 + coff] = d;
        }
    }
}

// ---------- kernel B: recurrent LSTM (C^T, 16-node tiles) + fused out linear ----------
// wave w owns channels [w*16,w*16+16) of ALL 4 gates for 16 nodes; C^T: row =
// channel (l4*4+q), col = node. Lane owns 4 ADJACENT channels of 1 node ->
// shfl-free h pack. h LDS: [node][ch] bf16, row stride 272B (17x16B).
template <int NOUT, int ACT, typename OutT>
__global__ __launch_bounds__(512, 4) void k_lstm_fused(
    const u32x2*  __restrict__ xu,      // 1KB gate-quad rows (scaled units)
    const int*    __restrict__ nbr,     // [N,16]
    const u32x4*  __restrict__ whh,     // 128 frags (A-operand, scaled)
    const u32x4*  __restrict__ wout,    // epilogue A-frags (K=256 concat)
    const float*  __restrict__ bout,    // [NOUT]
    const ushort* __restrict__ x_in,    // [N,128] bf16 (self input)
    OutT*         __restrict__ out,     // [N,NOUT]
    int N)
{
    constexpr int HSTR = 272;                        // 17 x 16B, b128-aligned
    __shared__ alignas(16) char h_lds[2][16 * HSTR]; // 2 x 4.25KB
    __shared__ uint32_t idxs[DEG * 16];              // prescaled byte offsets

    const int tid  = threadIdx.x;
    const int lane = tid & 63;
    const int w    = tid >> 6;
    const int col  = lane & 15;
    const int l4   = lane >> 4;
    const int node0 = blockIdx.x * 16;

    if (tid < DEG * 16) {               // idxs[t*16+m]
        int m = tid & 15, t = tid >> 4;
        int gn = node0 + m; if (gn >= N) gn = N - 1;
        idxs[t * 16 + m] = (uint32_t)nbr[gn * DEG + t] << 10;
    }
    if (tid < 16 * HSTR / 16)           // zero h(-1) = buf[0] (272 u32x4)
        ((u32x4*)h_lds[0])[tid] = u32x4{0u, 0u, 0u, 0u};

    // W_hh A-frags: 64 regs
    u32x4 wreg[4][4];
#pragma unroll
    for (int g = 0; g < 4; ++g)
#pragma unroll
        for (int ks = 0; ks < 4; ++ks)
            wreg[g][ks] = whh[((g * 8 + w) * 4 + ks) * 64 + lane];

    float cst[4];
#pragma unroll
    for (int r = 0; r < 4; ++r) cst[r] = 0.0f;

    const char* xu_c = (const char*)xu;
    const uint32_t goff = (uint32_t)(w * 128 + l4 * 32);  // slice byte in xu row
    const int rd0 = col * HSTR + l4 * 16;                 // + ks*64
    const int wr0 = col * HSTR + w * 32 + l4 * 8;

    __syncthreads();   // idxs + h(-1) zeros visible

    // prologue gather (step 0): 32B contiguous per (node, ch-quad)
    u32x4 vv[2];
    {
        const char* p0 = xu_c + idxs[col] + goff;
        vv[0] = *(const u32x4*)(p0);
        vv[1] = *(const u32x4*)(p0 + 16);
    }

#pragma unroll 1
    for (int t = 0; t < DEG; ++t) {
        const char* hr = h_lds[t & 1];
        char*       hw = h_lds[(t + 1) & 1];

        // ---- acc init: C^T element (ch = w*16+l4*4+q, node = col)
        f32x4 acc[4];
#pragma unroll
        for (int q = 0; q < 4; ++q) {
            uint32_t px = vv[q >> 1][(q & 1) * 2];
            uint32_t py = vv[q >> 1][(q & 1) * 2 + 1];
            acc[0][q] = __uint_as_float(px << 16);
            acc[1][q] = __uint_as_float(px & 0xFFFF0000u);
            acc[2][q] = __uint_as_float(py << 16);
            acc[3][q] = __uint_as_float(py & 0xFFFF0000u);
        }

        // ---- prefetch next step (vv fully consumed)
        if (t + 1 < DEG) {
            const char* p0 = xu_c + idxs[(t + 1) * 16 + col] + goff;
            vv[0] = *(const u32x4*)(p0);
            vv[1] = *(const u32x4*)(p0 + 16);
        }

        // ---- MFMA C^T: A = W_hh frags, B = h(t-1) from LDS
#pragma unroll
        for (int ks = 0; ks < 4; ++ks) {
            bf16x8 b = *(const bf16x8*)(hr + rd0 + ks * 64);
#pragma unroll
            for (int g = 0; g < 4; ++g)
                acc[g] = __builtin_amdgcn_mfma_f32_16x16x32_bf16(
                    __builtin_bit_cast(bf16x8, wreg[g][ks]), b, acc[g], 0, 0, 0);
        }

        // ---- cell: i,f,g tight chains + folded output stage (9 trans)
        float hv[4];
#pragma unroll
        for (int q = 0; q < 4; ++q) {
            float iv = sig2(acc[0][q]);
            float fv = sig2(acc[1][q]);
            float gv = tanh2(acc[2][q]);
            float cv = __fmaf_rn(fv, cst[q], iv * gv);
            cst[q] = cv;
            // sig(o)*tanh(c) = (1-Ec) * rcp((1+Eo)(1+Ec))
            float Eo = __builtin_amdgcn_exp2f(-acc[3][q]);
            float Ec = __builtin_amdgcn_exp2f(cv * NEG2_LOG2E);
            hv[q] = (1.0f - Ec) *
                    __builtin_amdgcn_rcpf((1.0f + Eo) * (1.0f + Ec));
        }
        u32x2 hp;
        hp.x = pack2bf16(hv[0], hv[1]);
        hp.y = pack2bf16(hv[2], hv[3]);
        *(u32x2*)(hw + wr0) = hp;

        __syncthreads();   // h(t) visible; WAR-safe via dbuf (1 barrier/step)
    }

    // ---- fused output linear: out = act([x|h] @ [Ws;Wn]^T + b), C^T MFMA
    // h(15) in h_lds[0] (t=15 wrote buf[16&1]=buf[0]).
    if (NOUT == 128 || w < 4) {
        const char* hf = h_lds[0];
        const int otile = (NOUT == 128) ? w : (w & 3);
        const int och0  = otile * 16 + l4 * 4;
        const float4 bq = *(const float4*)(bout + och0);
        const int gn = node0 + col;
        const int gx = (gn < N) ? gn : (N - 1);
        f32x4 acc = {bq.x, bq.y, bq.z, bq.w};
#pragma unroll
        for (int ks = 0; ks < 8; ++ks) {
            u32x4 af = wout[(otile * 8 + ks) * 64 + lane];
            bf16x8 bf_;
            if (ks < 4)
                bf_ = *(const bf16x8*)((const char*)x_in + (size_t)gx * 256 +
                                       ks * 64 + l4 * 16);
            else
                bf_ = *(const bf16x8*)(hf + col * HSTR + (ks - 4) * 64 + l4 * 16);
            acc = __builtin_amdgcn_mfma_f32_16x16x32_bf16(
                __builtin_bit_cast(bf16x8, af), bf_, acc, 0, 0, 0);
        }
        if (gn < N) {
            float av[4];
#pragma unroll
            for (int q = 0; q < 4; ++q)
                av[q] = (ACT == 0) ? fmaxf(acc[q], 0.0f) : fsigmoid(acc[q]);
            if constexpr (sizeof(OutT) == 2) {
                u32x2 o;
                o.x = pack2bf16(av[0], av[1]);
                o.y = pack2bf16(av[2], av[3]);
                *(u32x2*)((ushort*)out + (size_t)gn * NOUT + och0) = o;
            } else {
                f32x4 o = {av[0], av[1], av[2], av[3]};
                *(f32x4*)((float*)out + (size_t)gn * NOUT + och0) = o;
            }
        }
    }
}

extern "C" void kernel_launch(void* const* d_in, const int* in_sizes, int n_in,
                              void* d_out, int out_size, void* d_ws, size_t ws_size,
                              hipStream_t stream)
{
    const float* feats    = (const float*)d_in[0];
    const int*   nbr      = (const int*)  d_in[1];
    const float* w_ih1    = (const float*)d_in[2];
    const float* w_hh1    = (const float*)d_in[3];
    const float* b_ih1    = (const float*)d_in[4];
    const float* b_hh1    = (const float*)d_in[5];
    const float* w_self1  = (const float*)d_in[6];
    const float* w_neigh1 = (const float*)d_in[7];
    const float* b1       = (const float*)d_in[8];
    const float* w_ih2    = (const float*)d_in[9];
    const float* w_hh2    = (const float*)d_in[10];
    const float* b_ih2    = (const float*)d_in[11];
    const float* b_hh2    = (const float*)d_in[12];
    const float* w_self2  = (const float*)d_in[13];
    const float* w_neigh2 = (const float*)d_in[14];
    const float* b2       = (const float*)d_in[15];
    float* out = (float*)d_out;

    const int N = in_sizes[0] / IN;   // 50000
    const long long Nceil = (N + 63) & ~63LL;

    char* ws = (char*)d_ws;
    size_t off = 0;
    auto alloc = [&](size_t bytes) -> void* {
        void* p = (void*)(ws + off);
        off += (bytes + 255) & ~(size_t)255;
        return p;
    };
    u32x4*  wfrag_ih1 = (u32x4*)alloc(8192 * 16);
    u32x4*  wfrag_hh1 = (u32x4*)alloc(8192 * 16);
    u32x4*  wfrag_ih2 = (u32x4*)alloc(8192 * 16);
    u32x4*  wfrag_hh2 = (u32x4*)alloc(8192 * 16);
    u32x4*  wofrag1   = (u32x4*)alloc(4096 * 16);   // 64KB epilogue A-frags L1
    u32x4*  wofrag2   = (u32x4*)alloc(2048 * 16);   // 32KB epilogue A-frags L2
    ushort* feats_bf  = (ushort*)alloc((size_t)N * 128 * 2);
    ushort* out1      = (ushort*)alloc((size_t)N * 128 * 2);
    u32x2*  xu_buf    = (u32x2*)alloc((size_t)Nceil * 128 * 8);   // 51.25MB

    // prep
    k_pack_all<<<dim3(128), dim3(256), 0, stream>>>(w_ih1, wfrag_ih1, w_hh1, wfrag_hh1,
                                                    w_ih2, wfrag_ih2, w_hh2, wfrag_hh2);
    k_pack_out<<<dim3(24), dim3(256), 0, stream>>>(w_self1, w_neigh1, wofrag1,
                                                   w_self2, w_neigh2, wofrag2);
    k_cast_bf16<<<dim3((N * 128 / 4 + 255) / 256), dim3(256), 0, stream>>>(feats, feats_bf, N * 128);

    const int nblk64 = (int)(Nceil / 64);
    const int nblk16 = (N + 15) / 16;   // 3125 (exact for N=50000)

    // layer 1
    k_xu<<<dim3(nblk64), dim3(256), 0, stream>>>(feats_bf, wfrag_ih1, b_ih1, b_hh1, xu_buf, N);
    k_lstm_fused<128, 0, ushort><<<dim3(nblk16), dim3(512), 0, stream>>>(
        xu_buf, nbr, wfrag_hh1, wofrag1, b1, feats_bf, out1, N);

    // layer 2
    k_xu<<<dim3(nblk64), dim3(256), 0, stream>>>(out1, wfrag_ih2, b_ih2, b_hh2, xu_buf, N);
    k_lstm_fused<64, 1, float><<<dim3(nblk16), dim3(512), 0, stream>>>(
        xu_buf, nbr, wfrag_hh2, wofrag2, b2, out1, out, N);
}

// Round 12
// 485.267 us; speedup vs baseline: 1.3906x; 1.0258x over previous
//
#include <hip/hip_runtime.h>
#include <cstdint>
#include <cstddef>

// SAGE-LSTM R23: R22 + ig-fold retry (9 -> 8 trans/element).
// R22 post-mortem: BN=16 confirmed tail theory (occ 36.5->41.3, 196us) AND
// eliminated the last spill (WRITE_SIZE 28.1 -> 12.500 MB = exact output
// bytes; cst 8->4, vv 4->2 freed the regs). Trans issue = 94us of 196 wall.
// R23: retry R18's ig-fold under the new (lower) pressure:
//   sig(i)*tanh(g) = (1-Eg)*rcp((1+Ei)(1+Eg))   [3 trans]
//   sig(f) tight [2] + h-fold (R21-proven) [3]  => 8 trans/elem.
// Decision variable: WRITE_SIZE must stay exactly 12.5 MB (no spill);
// any increase -> revert to R22 and declare the structural ceiling.

constexpr int IN  = 128;
constexpr int DEG = 16;
#define LOG2E       1.4426950408889634f
#define TWO_LOG2E   2.8853900817779268f
#define NEG2_LOG2E -2.8853900817779268f

typedef short bf16x8 __attribute__((ext_vector_type(8)));
typedef float f32x4  __attribute__((ext_vector_type(4)));
typedef float f32x16 __attribute__((ext_vector_type(16)));
typedef unsigned int u32x4 __attribute__((ext_vector_type(4)));
typedef unsigned int u32x2 __attribute__((ext_vector_type(2)));

__device__ __forceinline__ float fsigmoid(float x) {   // unscaled input
    float e = __expf(-x);
    return __builtin_amdgcn_rcpf(1.0f + e);
}
// sigma(x) with y = x*log2e pre-scaled into the weights
__device__ __forceinline__ float sig2(float y) {
    float e = __builtin_amdgcn_exp2f(-y);
    return __builtin_amdgcn_rcpf(1.0f + e);
}
// tanh(x) with y = 2x*log2e pre-scaled
__device__ __forceinline__ float tanh2(float y) {
    float e = __builtin_amdgcn_exp2f(-y);
    return __fmaf_rn(2.0f, __builtin_amdgcn_rcpf(1.0f + e), -1.0f);
}
__device__ __forceinline__ uint32_t pack2bf16(float a, float b) {
    uint32_t ua = __float_as_uint(a) + 0x8000u;
    uint32_t ub = __float_as_uint(b) + 0x8000u;
    return (ua >> 16) | (ub & 0xFFFF0000u);
}

// ---------- prep kernels ----------

__global__ void k_cast_bf16(const float* __restrict__ src, ushort* __restrict__ dst, int n) {
    int i = (blockIdx.x * blockDim.x + threadIdx.x) * 4;
    if (i + 3 < n) {
        float4 v = *(const float4*)(src + i);
        uint2 d; d.x = pack2bf16(v.x, v.y); d.y = pack2bf16(v.z, v.w);
        *(uint2*)(dst + i) = d;
    } else {
        for (int k = i; k < n; ++k)
            dst[k] = (ushort)((__float_as_uint(src[k]) + 0x8000u) >> 16);
    }
}

// Pack all 4 [512 x 128] gate weights into MFMA fragment order, PRE-SCALED:
// gate rows i,f,o (rows 0..255, 384..511) x log2e; gate g (256..383) x 2log2e.
// ih (which 0,2): 32x32x16 B-frag (consumed by k_xu).
// hh (which 1,3): 16x16x32 frag (A-operand in k_lstm_fused).
__global__ void k_pack_all(const float* __restrict__ w0, u32x4* __restrict__ f0,
                           const float* __restrict__ w1, u32x4* __restrict__ f1,
                           const float* __restrict__ w2, u32x4* __restrict__ f2,
                           const float* __restrict__ w3, u32x4* __restrict__ f3) {
    int gt = blockIdx.x * 256 + threadIdx.x;     // 0..32767
    int which = gt >> 13;
    int tid  = gt & 8191;
    const float* wsrc = (which == 0) ? w0 : (which == 1) ? w1 : (which == 2) ? w2 : w3;
    u32x4* frag = (which == 0) ? f0 : (which == 1) ? f1 : (which == 2) ? f2 : f3;
    int lane = tid & 63;
    float v[8];
    int row;
    if ((which & 1) == 0) {
        int tile = (tid >> 6) & 15;
        int kst  = tid >> 10;
        row = tile * 32 + (lane & 31);
        int kbase = kst * 16 + (lane >> 5) * 8;
#pragma unroll
        for (int j = 0; j < 8; ++j) v[j] = wsrc[row * 128 + kbase + j];
    } else {
        int f  = tid >> 6;            // 0..127
        int ks = f & 3;
        int w8 = (f >> 2) & 7;
        int g  = f >> 5;
        row = g * 128 + w8 * 16 + (lane & 15);
        int kbase = ks * 32 + (lane >> 4) * 8;
#pragma unroll
        for (int j = 0; j < 8; ++j) v[j] = wsrc[row * 128 + kbase + j];
    }
    const float sc = ((row >> 7) == 2) ? TWO_LOG2E : LOG2E;
#pragma unroll
    for (int j = 0; j < 8; ++j) v[j] *= sc;
    u32x4 d;
    d.x = pack2bf16(v[0], v[1]);
    d.y = pack2bf16(v[2], v[3]);
    d.z = pack2bf16(v[4], v[5]);
    d.w = pack2bf16(v[6], v[7]);
    frag[tid] = d;
}

// Pack output-linear weights as A-frags over K=256 concat [Wself ; Wneigh].
// (UNSCALED - epilogue activations use natural units.)
__global__ void k_pack_out(const float* __restrict__ ws1, const float* __restrict__ wn1,
                           u32x4* __restrict__ f1,
                           const float* __restrict__ ws2, const float* __restrict__ wn2,
                           u32x4* __restrict__ f2) {
    int t = blockIdx.x * 256 + threadIdx.x;   // 0..6143
    int lane = t & 63;
    int row  = lane & 15;
    int kb   = (lane >> 4) * 8;
    float v[8];
    const float* ws; const float* wn; u32x4* dst; int p;
    if (t < 4096) { ws = ws1; wn = wn1; dst = f1; p = t; }
    else          { ws = ws2; wn = wn2; dst = f2; p = t - 4096; }
    int ks  = (p >> 6) & 7;
    int och = (p >> 9) * 16 + row;
    int kbase = ks * 32 + kb;
#pragma unroll
    for (int j = 0; j < 8; ++j) {
        int k = kbase + j;
        v[j] = (k < 128) ? ws[och * 128 + k] : wn[och * 128 + k - 128];
    }
    u32x4 d;
    d.x = pack2bf16(v[0], v[1]);
    d.y = pack2bf16(v[2], v[3]);
    d.z = pack2bf16(v[4], v[5]);
    d.w = pack2bf16(v[6], v[7]);
    dst[p] = d;
}

// ---------- kernel A: Xu = x @ W_ih^T + (b_ih+b_hh), gate-quad row store ----------
// biases pre-scaled to match the weight scaling (gate g x 2log2e, others x log2e).
__global__ __launch_bounds__(256, 2) void k_xu(
    const ushort* __restrict__ x,       // [N,128] bf16
    const u32x4*  __restrict__ wih,     // 8192 B-frags (32x32 layout, scaled)
    const float*  __restrict__ b_ih,    // [512]
    const float*  __restrict__ b_hh,    // [512]
    u32x2*        __restrict__ xu,      // [Nceil][128] u32x2 (1KB rows)
    int N)
{
    __shared__ u32x4 a_buf[16][66];

    const int tid   = threadIdx.x;
    const int lane  = tid & 63;
    const int w     = tid >> 6;
    const int mrow  = lane & 31;
    const int khalf = lane >> 5;
    const int node0 = blockIdx.x * 64;

    u32x4 wreg[8][4];
#pragma unroll
    for (int kst = 0; kst < 8; ++kst)
#pragma unroll
        for (int g = 0; g < 4; ++g)
            wreg[kst][g] = wih[(kst * 16 + g * 4 + w) * 64 + lane];

    float binit[4];
#pragma unroll
    for (int g = 0; g < 4; ++g) {
        int jj = g * 128 + w * 32 + mrow;
        binit[g] = (b_ih[jj] + b_hh[jj]) * ((g == 2) ? TWO_LOG2E : LOG2E);
    }

    {
        int m_st = tid >> 2, c4 = tid & 3;
        int gn = node0 + m_st; if (gn >= N) gn = N - 1;
        const u32x4* src = (const u32x4*)(x + (size_t)gn * IN);
#pragma unroll
        for (int q = 0; q < 4; ++q) {
            int kg = q * 4 + c4;
            a_buf[kg][m_st] = src[kg];
        }
    }
    __syncthreads();

    const int coff = w * 32 + mrow;
#pragma unroll 1
    for (int Mt = 0; Mt < 2; ++Mt) {
        f32x16 acc[4];
#pragma unroll
        for (int g = 0; g < 4; ++g)
#pragma unroll
            for (int r = 0; r < 16; ++r) acc[g][r] = binit[g];

#pragma unroll
        for (int kst = 0; kst < 8; ++kst) {
            bf16x8 a = __builtin_bit_cast(bf16x8, a_buf[kst * 2 + khalf][Mt * 32 + mrow]);
#pragma unroll
            for (int g = 0; g < 4; ++g)
                acc[g] = __builtin_amdgcn_mfma_f32_32x32x16_bf16(
                    a, __builtin_bit_cast(bf16x8, wreg[kst][g]), acc[g], 0, 0, 0);
        }

#pragma unroll
        for (int r = 0; r < 16; ++r) {
            int m = Mt * 32 + (r & 3) + 8 * (r >> 2) + 4 * khalf;
            u32x2 d;
            d.x = pack2bf16(acc[0][r], acc[1][r]);
            d.y = pack2bf16(acc[2][r], acc[3][r]);
            xu[(size_t)(node0 + m) * 128 + coff] = d;
        }
    }
}

// ---------- kernel B: recurrent LSTM (C^T, 16-node tiles) + fused out linear ----------
// wave w owns channels [w*16,w*16+16) of ALL 4 gates for 16 nodes; C^T: row =
// channel (l4*4+q), col = node. Lane owns 4 ADJACENT channels of 1 node ->
// shfl-free h pack. h LDS: [node][ch] bf16, row stride 272B (17x16B).
template <int NOUT, int ACT, typename OutT>
__global__ __launch_bounds__(512, 4) void k_lstm_fused(
    const u32x2*  __restrict__ xu,      // 1KB gate-quad rows (scaled units)
    const int*    __restrict__ nbr,     // [N,16]
    const u32x4*  __restrict__ whh,     // 128 frags (A-operand, scaled)
    const u32x4*  __restrict__ wout,    // epilogue A-frags (K=256 concat)
    const float*  __restrict__ bout,    // [NOUT]
    const ushort* __restrict__ x_in,    // [N,128] bf16 (self input)
    OutT*         __restrict__ out,     // [N,NOUT]
    int N)
{
    constexpr int HSTR = 272;                        // 17 x 16B, b128-aligned
    __shared__ alignas(16) char h_lds[2][16 * HSTR]; // 2 x 4.25KB
    __shared__ uint32_t idxs[DEG * 16];              // prescaled byte offsets

    const int tid  = threadIdx.x;
    const int lane = tid & 63;
    const int w    = tid >> 6;
    const int col  = lane & 15;
    const int l4   = lane >> 4;
    const int node0 = blockIdx.x * 16;

    if (tid < DEG * 16) {               // idxs[t*16+m]
        int m = tid & 15, t = tid >> 4;
        int gn = node0 + m; if (gn >= N) gn = N - 1;
        idxs[t * 16 + m] = (uint32_t)nbr[gn * DEG + t] << 10;
    }
    if (tid < 16 * HSTR / 16)           // zero h(-1) = buf[0] (272 u32x4)
        ((u32x4*)h_lds[0])[tid] = u32x4{0u, 0u, 0u, 0u};

    // W_hh A-frags: 64 regs
    u32x4 wreg[4][4];
#pragma unroll
    for (int g = 0; g < 4; ++g)
#pragma unroll
        for (int ks = 0; ks < 4; ++ks)
            wreg[g][ks] = whh[((g * 8 + w) * 4 + ks) * 64 + lane];

    float cst[4];
#pragma unroll
    for (int r = 0; r < 4; ++r) cst[r] = 0.0f;

    const char* xu_c = (const char*)xu;
    const uint32_t goff = (uint32_t)(w * 128 + l4 * 32);  // slice byte in xu row
    const int rd0 = col * HSTR + l4 * 16;                 // + ks*64
    const int wr0 = col * HSTR + w * 32 + l4 * 8;

    __syncthreads();   // idxs + h(-1) zeros visible

    // prologue gather (step 0): 32B contiguous per (node, ch-quad)
    u32x4 vv[2];
    {
        const char* p0 = xu_c + idxs[col] + goff;
        vv[0] = *(const u32x4*)(p0);
        vv[1] = *(const u32x4*)(p0 + 16);
    }

#pragma unroll 1
    for (int t = 0; t < DEG; ++t) {
        const char* hr = h_lds[t & 1];
        char*       hw = h_lds[(t + 1) & 1];

        // ---- acc init: C^T element (ch = w*16+l4*4+q, node = col)
        f32x4 acc[4];
#pragma unroll
        for (int q = 0; q < 4; ++q) {
            uint32_t px = vv[q >> 1][(q & 1) * 2];
            uint32_t py = vv[q >> 1][(q & 1) * 2 + 1];
            acc[0][q] = __uint_as_float(px << 16);
            acc[1][q] = __uint_as_float(px & 0xFFFF0000u);
            acc[2][q] = __uint_as_float(py << 16);
            acc[3][q] = __uint_as_float(py & 0xFFFF0000u);
        }

        // ---- prefetch next step (vv fully consumed)
        if (t + 1 < DEG) {
            const char* p0 = xu_c + idxs[(t + 1) * 16 + col] + goff;
            vv[0] = *(const u32x4*)(p0);
            vv[1] = *(const u32x4*)(p0 + 16);
        }

        // ---- MFMA C^T: A = W_hh frags, B = h(t-1) from LDS
#pragma unroll
        for (int ks = 0; ks < 4; ++ks) {
            bf16x8 b = *(const bf16x8*)(hr + rd0 + ks * 64);
#pragma unroll
            for (int g = 0; g < 4; ++g)
                acc[g] = __builtin_amdgcn_mfma_f32_16x16x32_bf16(
                    __builtin_bit_cast(bf16x8, wreg[g][ks]), b, acc[g], 0, 0, 0);
        }

        // ---- cell: ig-fold + f tight + folded output stage (8 trans)
        float hv[4];
#pragma unroll
        for (int q = 0; q < 4; ++q) {
            // sig(i)*tanh(g) = (1-Eg) * rcp((1+Ei)(1+Eg))
            float Ei = __builtin_amdgcn_exp2f(-acc[0][q]);
            float Eg = __builtin_amdgcn_exp2f(-acc[2][q]);
            float ig = (1.0f - Eg) *
                       __builtin_amdgcn_rcpf((1.0f + Ei) * (1.0f + Eg));
            float fv = sig2(acc[1][q]);
            float cv = __fmaf_rn(fv, cst[q], ig);
            cst[q] = cv;
            // sig(o)*tanh(c) = (1-Ec) * rcp((1+Eo)(1+Ec))
            float Eo = __builtin_amdgcn_exp2f(-acc[3][q]);
            float Ec = __builtin_amdgcn_exp2f(cv * NEG2_LOG2E);
            hv[q] = (1.0f - Ec) *
                    __builtin_amdgcn_rcpf((1.0f + Eo) * (1.0f + Ec));
        }
        u32x2 hp;
        hp.x = pack2bf16(hv[0], hv[1]);
        hp.y = pack2bf16(hv[2], hv[3]);
        *(u32x2*)(hw + wr0) = hp;

        __syncthreads();   // h(t) visible; WAR-safe via dbuf (1 barrier/step)
    }

    // ---- fused output linear: out = act([x|h] @ [Ws;Wn]^T + b), C^T MFMA
    // h(15) in h_lds[0] (t=15 wrote buf[16&1]=buf[0]).
    if (NOUT == 128 || w < 4) {
        const char* hf = h_lds[0];
        const int otile = (NOUT == 128) ? w : (w & 3);
        const int och0  = otile * 16 + l4 * 4;
        const float4 bq = *(const float4*)(bout + och0);
        const int gn = node0 + col;
        const int gx = (gn < N) ? gn : (N - 1);
        f32x4 acc = {bq.x, bq.y, bq.z, bq.w};
#pragma unroll
        for (int ks = 0; ks < 8; ++ks) {
            u32x4 af = wout[(otile * 8 + ks) * 64 + lane];
            bf16x8 bf_;
            if (ks < 4)
                bf_ = *(const bf16x8*)((const char*)x_in + (size_t)gx * 256 +
                                       ks * 64 + l4 * 16);
            else
                bf_ = *(const bf16x8*)(hf + col * HSTR + (ks - 4) * 64 + l4 * 16);
            acc = __builtin_amdgcn_mfma_f32_16x16x32_bf16(
                __builtin_bit_cast(bf16x8, af), bf_, acc, 0, 0, 0);
        }
        if (gn < N) {
            float av[4];
#pragma unroll
            for (int q = 0; q < 4; ++q)
                av[q] = (ACT == 0) ? fmaxf(acc[q], 0.0f) : fsigmoid(acc[q]);
            if constexpr (sizeof(OutT) == 2) {
                u32x2 o;
                o.x = pack2bf16(av[0], av[1]);
                o.y = pack2bf16(av[2], av[3]);
                *(u32x2*)((ushort*)out + (size_t)gn * NOUT + och0) = o;
            } else {
                f32x4 o = {av[0], av[1], av[2], av[3]};
                *(f32x4*)((float*)out + (size_t)gn * NOUT + och0) = o;
            }
        }
    }
}

extern "C" void kernel_launch(void* const* d_in, const int* in_sizes, int n_in,
                              void* d_out, int out_size, void* d_ws, size_t ws_size,
                              hipStream_t stream)
{
    const float* feats    = (const float*)d_in[0];
    const int*   nbr      = (const int*)  d_in[1];
    const float* w_ih1    = (const float*)d_in[2];
    const float* w_hh1    = (const float*)d_in[3];
    const float* b_ih1    = (const float*)d_in[4];
    const float* b_hh1    = (const float*)d_in[5];
    const float* w_self1  = (const float*)d_in[6];
    const float* w_neigh1 = (const float*)d_in[7];
    const float* b1       = (const float*)d_in[8];
    const float* w_ih2    = (const float*)d_in[9];
    const float* w_hh2    = (const float*)d_in[10];
    const float* b_ih2    = (const float*)d_in[11];
    const float* b_hh2    = (const float*)d_in[12];
    const float* w_self2  = (const float*)d_in[13];
    const float* w_neigh2 = (const float*)d_in[14];
    const float* b2       = (const float*)d_in[15];
    float* out = (float*)d_out;

    const int N = in_sizes[0] / IN;   // 50000
    const long long Nceil = (N + 63) & ~63LL;

    char* ws = (char*)d_ws;
    size_t off = 0;
    auto alloc = [&](size_t bytes) -> void* {
        void* p = (void*)(ws + off);
        off += (bytes + 255) & ~(size_t)255;
        return p;
    };
    u32x4*  wfrag_ih1 = (u32x4*)alloc(8192 * 16);
    u32x4*  wfrag_hh1 = (u32x4*)alloc(8192 * 16);
    u32x4*  wfrag_ih2 = (u32x4*)alloc(8192 * 16);
    u32x4*  wfrag_hh2 = (u32x4*)alloc(8192 * 16);
    u32x4*  wofrag1   = (u32x4*)alloc(4096 * 16);   // 64KB epilogue A-frags L1
    u32x4*  wofrag2   = (u32x4*)alloc(2048 * 16);   // 32KB epilogue A-frags L2
    ushort* feats_bf  = (ushort*)alloc((size_t)N * 128 * 2);
    ushort* out1      = (ushort*)alloc((size_t)N * 128 * 2);
    u32x2*  xu_buf    = (u32x2*)alloc((size_t)Nceil * 128 * 8);   // 51.25MB

    // prep
    k_pack_all<<<dim3(128), dim3(256), 0, stream>>>(w_ih1, wfrag_ih1, w_hh1, wfrag_hh1,
                                                    w_ih2, wfrag_ih2, w_hh2, wfrag_hh2);
    k_pack_out<<<dim3(24), dim3(256), 0, stream>>>(w_self1, w_neigh1, wofrag1,
                                                   w_self2, w_neigh2, wofrag2);
    k_cast_bf16<<<dim3((N * 128 / 4 + 255) / 256), dim3(256), 0, stream>>>(feats, feats_bf, N * 128);

    const int nblk64 = (int)(Nceil / 64);
    const int nblk16 = (N + 15) / 16;   // 3125 (exact for N=50000)

    // layer 1
    k_xu<<<dim3(nblk64), dim3(256), 0, stream>>>(feats_bf, wfrag_ih1, b_ih1, b_hh1, xu_buf, N);
    k_lstm_fused<128, 0, ushort><<<dim3(nblk16), dim3(512), 0, stream>>>(
        xu_buf, nbr, wfrag_hh1, wofrag1, b1, feats_bf, out1, N);

    // layer 2
    k_xu<<<dim3(nblk64), dim3(256), 0, stream>>>(out1, wfrag_ih2, b_ih2, b_hh2, xu_buf, N);
    k_lstm_fused<64, 1, float><<<dim3(nblk16), dim3(512), 0, stream>>>(
        xu_buf, nbr, wfrag_hh2, wofrag2, b2, out1, out, N);
}

// Round 13
// 479.587 us; speedup vs baseline: 1.4071x; 1.0118x over previous
//
#include <hip/hip_runtime.h>
#include <cstdint>
#include <cstddef>

// SAGE-LSTM R24: R23 + full c-path common-denominator fold (8 -> 7 trans/elem).
// R23 validated the ig-fold at BN=16 (WRITE_SIZE held 12.500 MB, VGPR 64->60).
// R24 applies the last fold: merge sig(f)'s rcp into the ig rcp (R17's math,
// which PASSED numerically at R17 but spilled at BN=32's zero headroom):
//   c' = [c(1+Ei)(1+Eg) + (1-Eg)(1+Ef)] * rcp((1+Ef)(1+Ei)(1+Eg))
//   h  = (1-Ec) * rcp((1+Eo)(1+Ec))
// 5 exp + 2 rcp = 7 trans/elem = the floor for this activation set.
// Decision variable: WRITE_SIZE must stay exactly 12.5 MB; any increase ->
// revert to R23 and declare the structural ceiling.

constexpr int IN  = 128;
constexpr int DEG = 16;
#define LOG2E       1.4426950408889634f
#define TWO_LOG2E   2.8853900817779268f
#define NEG2_LOG2E -2.8853900817779268f

typedef short bf16x8 __attribute__((ext_vector_type(8)));
typedef float f32x4  __attribute__((ext_vector_type(4)));
typedef float f32x16 __attribute__((ext_vector_type(16)));
typedef unsigned int u32x4 __attribute__((ext_vector_type(4)));
typedef unsigned int u32x2 __attribute__((ext_vector_type(2)));

__device__ __forceinline__ float fsigmoid(float x) {   // unscaled input
    float e = __expf(-x);
    return __builtin_amdgcn_rcpf(1.0f + e);
}
__device__ __forceinline__ uint32_t pack2bf16(float a, float b) {
    uint32_t ua = __float_as_uint(a) + 0x8000u;
    uint32_t ub = __float_as_uint(b) + 0x8000u;
    return (ua >> 16) | (ub & 0xFFFF0000u);
}

// ---------- prep kernels ----------

__global__ void k_cast_bf16(const float* __restrict__ src, ushort* __restrict__ dst, int n) {
    int i = (blockIdx.x * blockDim.x + threadIdx.x) * 4;
    if (i + 3 < n) {
        float4 v = *(const float4*)(src + i);
        uint2 d; d.x = pack2bf16(v.x, v.y); d.y = pack2bf16(v.z, v.w);
        *(uint2*)(dst + i) = d;
    } else {
        for (int k = i; k < n; ++k)
            dst[k] = (ushort)((__float_as_uint(src[k]) + 0x8000u) >> 16);
    }
}

// Pack all 4 [512 x 128] gate weights into MFMA fragment order, PRE-SCALED:
// gate rows i,f,o (rows 0..255, 384..511) x log2e; gate g (256..383) x 2log2e.
// ih (which 0,2): 32x32x16 B-frag (consumed by k_xu).
// hh (which 1,3): 16x16x32 frag (A-operand in k_lstm_fused).
__global__ void k_pack_all(const float* __restrict__ w0, u32x4* __restrict__ f0,
                           const float* __restrict__ w1, u32x4* __restrict__ f1,
                           const float* __restrict__ w2, u32x4* __restrict__ f2,
                           const float* __restrict__ w3, u32x4* __restrict__ f3) {
    int gt = blockIdx.x * 256 + threadIdx.x;     // 0..32767
    int which = gt >> 13;
    int tid  = gt & 8191;
    const float* wsrc = (which == 0) ? w0 : (which == 1) ? w1 : (which == 2) ? w2 : w3;
    u32x4* frag = (which == 0) ? f0 : (which == 1) ? f1 : (which == 2) ? f2 : f3;
    int lane = tid & 63;
    float v[8];
    int row;
    if ((which & 1) == 0) {
        int tile = (tid >> 6) & 15;
        int kst  = tid >> 10;
        row = tile * 32 + (lane & 31);
        int kbase = kst * 16 + (lane >> 5) * 8;
#pragma unroll
        for (int j = 0; j < 8; ++j) v[j] = wsrc[row * 128 + kbase + j];
    } else {
        int f  = tid >> 6;            // 0..127
        int ks = f & 3;
        int w8 = (f >> 2) & 7;
        int g  = f >> 5;
        row = g * 128 + w8 * 16 + (lane & 15);
        int kbase = ks * 32 + (lane >> 4) * 8;
#pragma unroll
        for (int j = 0; j < 8; ++j) v[j] = wsrc[row * 128 + kbase + j];
    }
    const float sc = ((row >> 7) == 2) ? TWO_LOG2E : LOG2E;
#pragma unroll
    for (int j = 0; j < 8; ++j) v[j] *= sc;
    u32x4 d;
    d.x = pack2bf16(v[0], v[1]);
    d.y = pack2bf16(v[2], v[3]);
    d.z = pack2bf16(v[4], v[5]);
    d.w = pack2bf16(v[6], v[7]);
    frag[tid] = d;
}

// Pack output-linear weights as A-frags over K=256 concat [Wself ; Wneigh].
// (UNSCALED - epilogue activations use natural units.)
__global__ void k_pack_out(const float* __restrict__ ws1, const float* __restrict__ wn1,
                           u32x4* __restrict__ f1,
                           const float* __restrict__ ws2, const float* __restrict__ wn2,
                           u32x4* __restrict__ f2) {
    int t = blockIdx.x * 256 + threadIdx.x;   // 0..6143
    int lane = t & 63;
    int row  = lane & 15;
    int kb   = (lane >> 4) * 8;
    float v[8];
    const float* ws; const float* wn; u32x4* dst; int p;
    if (t < 4096) { ws = ws1; wn = wn1; dst = f1; p = t; }
    else          { ws = ws2; wn = wn2; dst = f2; p = t - 4096; }
    int ks  = (p >> 6) & 7;
    int och = (p >> 9) * 16 + row;
    int kbase = ks * 32 + kb;
#pragma unroll
    for (int j = 0; j < 8; ++j) {
        int k = kbase + j;
        v[j] = (k < 128) ? ws[och * 128 + k] : wn[och * 128 + k - 128];
    }
    u32x4 d;
    d.x = pack2bf16(v[0], v[1]);
    d.y = pack2bf16(v[2], v[3]);
    d.z = pack2bf16(v[4], v[5]);
    d.w = pack2bf16(v[6], v[7]);
    dst[p] = d;
}

// ---------- kernel A: Xu = x @ W_ih^T + (b_ih+b_hh), gate-quad row store ----------
// biases pre-scaled to match the weight scaling (gate g x 2log2e, others x log2e).
__global__ __launch_bounds__(256, 2) void k_xu(
    const ushort* __restrict__ x,       // [N,128] bf16
    const u32x4*  __restrict__ wih,     // 8192 B-frags (32x32 layout, scaled)
    const float*  __restrict__ b_ih,    // [512]
    const float*  __restrict__ b_hh,    // [512]
    u32x2*        __restrict__ xu,      // [Nceil][128] u32x2 (1KB rows)
    int N)
{
    __shared__ u32x4 a_buf[16][66];

    const int tid   = threadIdx.x;
    const int lane  = tid & 63;
    const int w     = tid >> 6;
    const int mrow  = lane & 31;
    const int khalf = lane >> 5;
    const int node0 = blockIdx.x * 64;

    u32x4 wreg[8][4];
#pragma unroll
    for (int kst = 0; kst < 8; ++kst)
#pragma unroll
        for (int g = 0; g < 4; ++g)
            wreg[kst][g] = wih[(kst * 16 + g * 4 + w) * 64 + lane];

    float binit[4];
#pragma unroll
    for (int g = 0; g < 4; ++g) {
        int jj = g * 128 + w * 32 + mrow;
        binit[g] = (b_ih[jj] + b_hh[jj]) * ((g == 2) ? TWO_LOG2E : LOG2E);
    }

    {
        int m_st = tid >> 2, c4 = tid & 3;
        int gn = node0 + m_st; if (gn >= N) gn = N - 1;
        const u32x4* src = (const u32x4*)(x + (size_t)gn * IN);
#pragma unroll
        for (int q = 0; q < 4; ++q) {
            int kg = q * 4 + c4;
            a_buf[kg][m_st] = src[kg];
        }
    }
    __syncthreads();

    const int coff = w * 32 + mrow;
#pragma unroll 1
    for (int Mt = 0; Mt < 2; ++Mt) {
        f32x16 acc[4];
#pragma unroll
        for (int g = 0; g < 4; ++g)
#pragma unroll
            for (int r = 0; r < 16; ++r) acc[g][r] = binit[g];

#pragma unroll
        for (int kst = 0; kst < 8; ++kst) {
            bf16x8 a = __builtin_bit_cast(bf16x8, a_buf[kst * 2 + khalf][Mt * 32 + mrow]);
#pragma unroll
            for (int g = 0; g < 4; ++g)
                acc[g] = __builtin_amdgcn_mfma_f32_32x32x16_bf16(
                    a, __builtin_bit_cast(bf16x8, wreg[kst][g]), acc[g], 0, 0, 0);
        }

#pragma unroll
        for (int r = 0; r < 16; ++r) {
            int m = Mt * 32 + (r & 3) + 8 * (r >> 2) + 4 * khalf;
            u32x2 d;
            d.x = pack2bf16(acc[0][r], acc[1][r]);
            d.y = pack2bf16(acc[2][r], acc[3][r]);
            xu[(size_t)(node0 + m) * 128 + coff] = d;
        }
    }
}

// ---------- kernel B: recurrent LSTM (C^T, 16-node tiles) + fused out linear ----------
// wave w owns channels [w*16,w*16+16) of ALL 4 gates for 16 nodes; C^T: row =
// channel (l4*4+q), col = node. Lane owns 4 ADJACENT channels of 1 node ->
// shfl-free h pack. h LDS: [node][ch] bf16, row stride 272B (17x16B).
template <int NOUT, int ACT, typename OutT>
__global__ __launch_bounds__(512, 4) void k_lstm_fused(
    const u32x2*  __restrict__ xu,      // 1KB gate-quad rows (scaled units)
    const int*    __restrict__ nbr,     // [N,16]
    const u32x4*  __restrict__ whh,     // 128 frags (A-operand, scaled)
    const u32x4*  __restrict__ wout,    // epilogue A-frags (K=256 concat)
    const float*  __restrict__ bout,    // [NOUT]
    const ushort* __restrict__ x_in,    // [N,128] bf16 (self input)
    OutT*         __restrict__ out,     // [N,NOUT]
    int N)
{
    constexpr int HSTR = 272;                        // 17 x 16B, b128-aligned
    __shared__ alignas(16) char h_lds[2][16 * HSTR]; // 2 x 4.25KB
    __shared__ uint32_t idxs[DEG * 16];              // prescaled byte offsets

    const int tid  = threadIdx.x;
    const int lane = tid & 63;
    const int w    = tid >> 6;
    const int col  = lane & 15;
    const int l4   = lane >> 4;
    const int node0 = blockIdx.x * 16;

    if (tid < DEG * 16) {               // idxs[t*16+m]
        int m = tid & 15, t = tid >> 4;
        int gn = node0 + m; if (gn >= N) gn = N - 1;
        idxs[t * 16 + m] = (uint32_t)nbr[gn * DEG + t] << 10;
    }
    if (tid < 16 * HSTR / 16)           // zero h(-1) = buf[0] (272 u32x4)
        ((u32x4*)h_lds[0])[tid] = u32x4{0u, 0u, 0u, 0u};

    // W_hh A-frags: 64 regs
    u32x4 wreg[4][4];
#pragma unroll
    for (int g = 0; g < 4; ++g)
#pragma unroll
        for (int ks = 0; ks < 4; ++ks)
            wreg[g][ks] = whh[((g * 8 + w) * 4 + ks) * 64 + lane];

    float cst[4];
#pragma unroll
    for (int r = 0; r < 4; ++r) cst[r] = 0.0f;

    const char* xu_c = (const char*)xu;
    const uint32_t goff = (uint32_t)(w * 128 + l4 * 32);  // slice byte in xu row
    const int rd0 = col * HSTR + l4 * 16;                 // + ks*64
    const int wr0 = col * HSTR + w * 32 + l4 * 8;

    __syncthreads();   // idxs + h(-1) zeros visible

    // prologue gather (step 0): 32B contiguous per (node, ch-quad)
    u32x4 vv[2];
    {
        const char* p0 = xu_c + idxs[col] + goff;
        vv[0] = *(const u32x4*)(p0);
        vv[1] = *(const u32x4*)(p0 + 16);
    }

#pragma unroll 1
    for (int t = 0; t < DEG; ++t) {
        const char* hr = h_lds[t & 1];
        char*       hw = h_lds[(t + 1) & 1];

        // ---- acc init: C^T element (ch = w*16+l4*4+q, node = col)
        f32x4 acc[4];
#pragma unroll
        for (int q = 0; q < 4; ++q) {
            uint32_t px = vv[q >> 1][(q & 1) * 2];
            uint32_t py = vv[q >> 1][(q & 1) * 2 + 1];
            acc[0][q] = __uint_as_float(px << 16);
            acc[1][q] = __uint_as_float(px & 0xFFFF0000u);
            acc[2][q] = __uint_as_float(py << 16);
            acc[3][q] = __uint_as_float(py & 0xFFFF0000u);
        }

        // ---- prefetch next step (vv fully consumed)
        if (t + 1 < DEG) {
            const char* p0 = xu_c + idxs[(t + 1) * 16 + col] + goff;
            vv[0] = *(const u32x4*)(p0);
            vv[1] = *(const u32x4*)(p0 + 16);
        }

        // ---- MFMA C^T: A = W_hh frags, B = h(t-1) from LDS
#pragma unroll
        for (int ks = 0; ks < 4; ++ks) {
            bf16x8 b = *(const bf16x8*)(hr + rd0 + ks * 64);
#pragma unroll
            for (int g = 0; g < 4; ++g)
                acc[g] = __builtin_amdgcn_mfma_f32_16x16x32_bf16(
                    __builtin_bit_cast(bf16x8, wreg[g][ks]), b, acc[g], 0, 0, 0);
        }

        // ---- cell: full c-path fold + folded output stage (7 trans)
        float hv[4];
#pragma unroll
        for (int q = 0; q < 4; ++q) {
            // c' = [c(1+Ei)(1+Eg) + (1-Eg)(1+Ef)] * rcp((1+Ef)(1+Ei)(1+Eg))
            float Ei = __builtin_amdgcn_exp2f(-acc[0][q]);
            float Eg = __builtin_amdgcn_exp2f(-acc[2][q]);
            float Ef = __builtin_amdgcn_exp2f(-acc[1][q]);
            float p  = (1.0f + Ei) * (1.0f + Eg);
            float num = __fmaf_rn(cst[q], p, (1.0f - Eg) * (1.0f + Ef));
            float cv = num * __builtin_amdgcn_rcpf(p * (1.0f + Ef));
            cst[q] = cv;
            // sig(o)*tanh(c) = (1-Ec) * rcp((1+Eo)(1+Ec))
            float Eo = __builtin_amdgcn_exp2f(-acc[3][q]);
            float Ec = __builtin_amdgcn_exp2f(cv * NEG2_LOG2E);
            hv[q] = (1.0f - Ec) *
                    __builtin_amdgcn_rcpf((1.0f + Eo) * (1.0f + Ec));
        }
        u32x2 hp;
        hp.x = pack2bf16(hv[0], hv[1]);
        hp.y = pack2bf16(hv[2], hv[3]);
        *(u32x2*)(hw + wr0) = hp;

        __syncthreads();   // h(t) visible; WAR-safe via dbuf (1 barrier/step)
    }

    // ---- fused output linear: out = act([x|h] @ [Ws;Wn]^T + b), C^T MFMA
    // h(15) in h_lds[0] (t=15 wrote buf[16&1]=buf[0]).
    if (NOUT == 128 || w < 4) {
        const char* hf = h_lds[0];
        const int otile = (NOUT == 128) ? w : (w & 3);
        const int och0  = otile * 16 + l4 * 4;
        const float4 bq = *(const float4*)(bout + och0);
        const int gn = node0 + col;
        const int gx = (gn < N) ? gn : (N - 1);
        f32x4 acc = {bq.x, bq.y, bq.z, bq.w};
#pragma unroll
        for (int ks = 0; ks < 8; ++ks) {
            u32x4 af = wout[(otile * 8 + ks) * 64 + lane];
            bf16x8 bf_;
            if (ks < 4)
                bf_ = *(const bf16x8*)((const char*)x_in + (size_t)gx * 256 +
                                       ks * 64 + l4 * 16);
            else
                bf_ = *(const bf16x8*)(hf + col * HSTR + (ks - 4) * 64 + l4 * 16);
            acc = __builtin_amdgcn_mfma_f32_16x16x32_bf16(
                __builtin_bit_cast(bf16x8, af), bf_, acc, 0, 0, 0);
        }
        if (gn < N) {
            float av[4];
#pragma unroll
            for (int q = 0; q < 4; ++q)
                av[q] = (ACT == 0) ? fmaxf(acc[q], 0.0f) : fsigmoid(acc[q]);
            if constexpr (sizeof(OutT) == 2) {
                u32x2 o;
                o.x = pack2bf16(av[0], av[1]);
                o.y = pack2bf16(av[2], av[3]);
                *(u32x2*)((ushort*)out + (size_t)gn * NOUT + och0) = o;
            } else {
                f32x4 o = {av[0], av[1], av[2], av[3]};
                *(f32x4*)((float*)out + (size_t)gn * NOUT + och0) = o;
            }
        }
    }
}

extern "C" void kernel_launch(void* const* d_in, const int* in_sizes, int n_in,
                              void* d_out, int out_size, void* d_ws, size_t ws_size,
                              hipStream_t stream)
{
    const float* feats    = (const float*)d_in[0];
    const int*   nbr      = (const int*)  d_in[1];
    const float* w_ih1    = (const float*)d_in[2];
    const float* w_hh1    = (const float*)d_in[3];
    const float* b_ih1    = (const float*)d_in[4];
    const float* b_hh1    = (const float*)d_in[5];
    const float* w_self1  = (const float*)d_in[6];
    const float* w_neigh1 = (const float*)d_in[7];
    const float* b1       = (const float*)d_in[8];
    const float* w_ih2    = (const float*)d_in[9];
    const float* w_hh2    = (const float*)d_in[10];
    const float* b_ih2    = (const float*)d_in[11];
    const float* b_hh2    = (const float*)d_in[12];
    const float* w_self2  = (const float*)d_in[13];
    const float* w_neigh2 = (const float*)d_in[14];
    const float* b2       = (const float*)d_in[15];
    float* out = (float*)d_out;

    const int N = in_sizes[0] / IN;   // 50000
    const long long Nceil = (N + 63) & ~63LL;

    char* ws = (char*)d_ws;
    size_t off = 0;
    auto alloc = [&](size_t bytes) -> void* {
        void* p = (void*)(ws + off);
        off += (bytes + 255) & ~(size_t)255;
        return p;
    };
    u32x4*  wfrag_ih1 = (u32x4*)alloc(8192 * 16);
    u32x4*  wfrag_hh1 = (u32x4*)alloc(8192 * 16);
    u32x4*  wfrag_ih2 = (u32x4*)alloc(8192 * 16);
    u32x4*  wfrag_hh2 = (u32x4*)alloc(8192 * 16);
    u32x4*  wofrag1   = (u32x4*)alloc(4096 * 16);   // 64KB epilogue A-frags L1
    u32x4*  wofrag2   = (u32x4*)alloc(2048 * 16);   // 32KB epilogue A-frags L2
    ushort* feats_bf  = (ushort*)alloc((size_t)N * 128 * 2);
    ushort* out1      = (ushort*)alloc((size_t)N * 128 * 2);
    u32x2*  xu_buf    = (u32x2*)alloc((size_t)Nceil * 128 * 8);   // 51.25MB

    // prep
    k_pack_all<<<dim3(128), dim3(256), 0, stream>>>(w_ih1, wfrag_ih1, w_hh1, wfrag_hh1,
                                                    w_ih2, wfrag_ih2, w_hh2, wfrag_hh2);
    k_pack_out<<<dim3(24), dim3(256), 0, stream>>>(w_self1, w_neigh1, wofrag1,
                                                   w_self2, w_neigh2, wofrag2);
    k_cast_bf16<<<dim3((N * 128 / 4 + 255) / 256), dim3(256), 0, stream>>>(feats, feats_bf, N * 128);

    const int nblk64 = (int)(Nceil / 64);
    const int nblk16 = (N + 15) / 16;   // 3125 (exact for N=50000)

    // layer 1
    k_xu<<<dim3(nblk64), dim3(256), 0, stream>>>(feats_bf, wfrag_ih1, b_ih1, b_hh1, xu_buf, N);
    k_lstm_fused<128, 0, ushort><<<dim3(nblk16), dim3(512), 0, stream>>>(
        xu_buf, nbr, wfrag_hh1, wofrag1, b1, feats_bf, out1, N);

    // layer 2
    k_xu<<<dim3(nblk64), dim3(256), 0, stream>>>(out1, wfrag_ih2, b_ih2, b_hh2, xu_buf, N);
    k_lstm_fused<64, 1, float><<<dim3(nblk16), dim3(512), 0, stream>>>(
        xu_buf, nbr, wfrag_hh2, wofrag2, b2, out1, out, N);
}

// Round 14
// 473.887 us; speedup vs baseline: 1.4240x; 1.0120x over previous
//
#include <hip/hip_runtime.h>
#include <cstdint>
#include <cstddef>

// SAGE-LSTM R25: cast-fusion into k_xu + setprio(1) around lstm MFMA cluster.
// R24 post-mortem: 7-trans fold landed (issue -10us) but wall -0.8us ->
// stall-conversion collapsed; cell surgery exhausted (7 = activation floor).
// Remaining structure: ~87us convoy stalls (8-wave barrier-locked blocks,
// 2 independent blocks/CU at the 128-reg tier) + 13% tail.
// R25: (1) k_xu<CVT=1> reads fp32 feats, converts in staging, writes the bf16
//      copy -> deletes k_cast's full pass (net -4us, safe).
//      (2) s_setprio(1) around lstm MFMA (T5): phase-diverse blocks/CU may
//      arbitrate better. DECISION RULE: lstm dur > 192.8us -> revert setprio.

constexpr int IN  = 128;
constexpr int DEG = 16;
#define LOG2E       1.4426950408889634f
#define TWO_LOG2E   2.8853900817779268f
#define NEG2_LOG2E -2.8853900817779268f

typedef short bf16x8 __attribute__((ext_vector_type(8)));
typedef float f32x4  __attribute__((ext_vector_type(4)));
typedef float f32x16 __attribute__((ext_vector_type(16)));
typedef unsigned int u32x4 __attribute__((ext_vector_type(4)));
typedef unsigned int u32x2 __attribute__((ext_vector_type(2)));

__device__ __forceinline__ float fsigmoid(float x) {   // unscaled input
    float e = __expf(-x);
    return __builtin_amdgcn_rcpf(1.0f + e);
}
__device__ __forceinline__ uint32_t pack2bf16(float a, float b) {
    uint32_t ua = __float_as_uint(a) + 0x8000u;
    uint32_t ub = __float_as_uint(b) + 0x8000u;
    return (ua >> 16) | (ub & 0xFFFF0000u);
}

// ---------- prep kernels ----------

// Pack all 4 [512 x 128] gate weights into MFMA fragment order, PRE-SCALED:
// gate rows i,f,o (rows 0..255, 384..511) x log2e; gate g (256..383) x 2log2e.
// ih (which 0,2): 32x32x16 B-frag (consumed by k_xu).
// hh (which 1,3): 16x16x32 frag (A-operand in k_lstm_fused).
__global__ void k_pack_all(const float* __restrict__ w0, u32x4* __restrict__ f0,
                           const float* __restrict__ w1, u32x4* __restrict__ f1,
                           const float* __restrict__ w2, u32x4* __restrict__ f2,
                           const float* __restrict__ w3, u32x4* __restrict__ f3) {
    int gt = blockIdx.x * 256 + threadIdx.x;     // 0..32767
    int which = gt >> 13;
    int tid  = gt & 8191;
    const float* wsrc = (which == 0) ? w0 : (which == 1) ? w1 : (which == 2) ? w2 : w3;
    u32x4* frag = (which == 0) ? f0 : (which == 1) ? f1 : (which == 2) ? f2 : f3;
    int lane = tid & 63;
    float v[8];
    int row;
    if ((which & 1) == 0) {
        int tile = (tid >> 6) & 15;
        int kst  = tid >> 10;
        row = tile * 32 + (lane & 31);
        int kbase = kst * 16 + (lane >> 5) * 8;
#pragma unroll
        for (int j = 0; j < 8; ++j) v[j] = wsrc[row * 128 + kbase + j];
    } else {
        int f  = tid >> 6;            // 0..127
        int ks = f & 3;
        int w8 = (f >> 2) & 7;
        int g  = f >> 5;
        row = g * 128 + w8 * 16 + (lane & 15);
        int kbase = ks * 32 + (lane >> 4) * 8;
#pragma unroll
        for (int j = 0; j < 8; ++j) v[j] = wsrc[row * 128 + kbase + j];
    }
    const float sc = ((row >> 7) == 2) ? TWO_LOG2E : LOG2E;
#pragma unroll
    for (int j = 0; j < 8; ++j) v[j] *= sc;
    u32x4 d;
    d.x = pack2bf16(v[0], v[1]);
    d.y = pack2bf16(v[2], v[3]);
    d.z = pack2bf16(v[4], v[5]);
    d.w = pack2bf16(v[6], v[7]);
    frag[tid] = d;
}

// Pack output-linear weights as A-frags over K=256 concat [Wself ; Wneigh].
// (UNSCALED - epilogue activations use natural units.)
__global__ void k_pack_out(const float* __restrict__ ws1, const float* __restrict__ wn1,
                           u32x4* __restrict__ f1,
                           const float* __restrict__ ws2, const float* __restrict__ wn2,
                           u32x4* __restrict__ f2) {
    int t = blockIdx.x * 256 + threadIdx.x;   // 0..6143
    int lane = t & 63;
    int row  = lane & 15;
    int kb   = (lane >> 4) * 8;
    float v[8];
    const float* ws; const float* wn; u32x4* dst; int p;
    if (t < 4096) { ws = ws1; wn = wn1; dst = f1; p = t; }
    else          { ws = ws2; wn = wn2; dst = f2; p = t - 4096; }
    int ks  = (p >> 6) & 7;
    int och = (p >> 9) * 16 + row;
    int kbase = ks * 32 + kb;
#pragma unroll
    for (int j = 0; j < 8; ++j) {
        int k = kbase + j;
        v[j] = (k < 128) ? ws[och * 128 + k] : wn[och * 128 + k - 128];
    }
    u32x4 d;
    d.x = pack2bf16(v[0], v[1]);
    d.y = pack2bf16(v[2], v[3]);
    d.z = pack2bf16(v[4], v[5]);
    d.w = pack2bf16(v[6], v[7]);
    dst[p] = d;
}

// ---------- kernel A: Xu = x @ W_ih^T + (b_ih+b_hh), gate-quad row store ----------
// biases pre-scaled to match the weight scaling (gate g x 2log2e, others x log2e).
// CVT=1: xin is fp32; convert during staging and emit bf16 copy to xbf.
template <int CVT>
__global__ __launch_bounds__(256, 2) void k_xu(
    const void*   __restrict__ xin,     // CVT ? f32[N][128] : bf16[N][128]
    ushort*       __restrict__ xbf,     // CVT=1: bf16 copy out
    const u32x4*  __restrict__ wih,     // 8192 B-frags (32x32 layout, scaled)
    const float*  __restrict__ b_ih,    // [512]
    const float*  __restrict__ b_hh,    // [512]
    u32x2*        __restrict__ xu,      // [Nceil][128] u32x2 (1KB rows)
    int N)
{
    __shared__ u32x4 a_buf[16][66];

    const int tid   = threadIdx.x;
    const int lane  = tid & 63;
    const int w     = tid >> 6;
    const int mrow  = lane & 31;
    const int khalf = lane >> 5;
    const int node0 = blockIdx.x * 64;

    u32x4 wreg[8][4];
#pragma unroll
    for (int kst = 0; kst < 8; ++kst)
#pragma unroll
        for (int g = 0; g < 4; ++g)
            wreg[kst][g] = wih[(kst * 16 + g * 4 + w) * 64 + lane];

    float binit[4];
#pragma unroll
    for (int g = 0; g < 4; ++g) {
        int jj = g * 128 + w * 32 + mrow;
        binit[g] = (b_ih[jj] + b_hh[jj]) * ((g == 2) ? TWO_LOG2E : LOG2E);
    }

    {
        int m_st = tid >> 2, c4 = tid & 3;
        int gn = node0 + m_st; if (gn >= N) gn = N - 1;
        if constexpr (CVT) {
            const float* src = (const float*)xin + (size_t)gn * IN;
#pragma unroll
            for (int q = 0; q < 4; ++q) {
                int kg = q * 4 + c4;
                float4 f0 = *(const float4*)(src + kg * 8);
                float4 f1 = *(const float4*)(src + kg * 8 + 4);
                u32x4 d;
                d.x = pack2bf16(f0.x, f0.y);
                d.y = pack2bf16(f0.z, f0.w);
                d.z = pack2bf16(f1.x, f1.y);
                d.w = pack2bf16(f1.z, f1.w);
                a_buf[kg][m_st] = d;
                *(u32x4*)(xbf + (size_t)gn * IN + kg * 8) = d;
            }
        } else {
            const u32x4* src = (const u32x4*)((const ushort*)xin + (size_t)gn * IN);
#pragma unroll
            for (int q = 0; q < 4; ++q) {
                int kg = q * 4 + c4;
                a_buf[kg][m_st] = src[kg];
            }
        }
    }
    __syncthreads();

    const int coff = w * 32 + mrow;
#pragma unroll 1
    for (int Mt = 0; Mt < 2; ++Mt) {
        f32x16 acc[4];
#pragma unroll
        for (int g = 0; g < 4; ++g)
#pragma unroll
            for (int r = 0; r < 16; ++r) acc[g][r] = binit[g];

#pragma unroll
        for (int kst = 0; kst < 8; ++kst) {
            bf16x8 a = __builtin_bit_cast(bf16x8, a_buf[kst * 2 + khalf][Mt * 32 + mrow]);
#pragma unroll
            for (int g = 0; g < 4; ++g)
                acc[g] = __builtin_amdgcn_mfma_f32_32x32x16_bf16(
                    a, __builtin_bit_cast(bf16x8, wreg[kst][g]), acc[g], 0, 0, 0);
        }

#pragma unroll
        for (int r = 0; r < 16; ++r) {
            int m = Mt * 32 + (r & 3) + 8 * (r >> 2) + 4 * khalf;
            u32x2 d;
            d.x = pack2bf16(acc[0][r], acc[1][r]);
            d.y = pack2bf16(acc[2][r], acc[3][r]);
            xu[(size_t)(node0 + m) * 128 + coff] = d;
        }
    }
}

// ---------- kernel B: recurrent LSTM (C^T, 16-node tiles) + fused out linear ----------
// wave w owns channels [w*16,w*16+16) of ALL 4 gates for 16 nodes; C^T: row =
// channel (l4*4+q), col = node. Lane owns 4 ADJACENT channels of 1 node ->
// shfl-free h pack. h LDS: [node][ch] bf16, row stride 272B (17x16B).
template <int NOUT, int ACT, typename OutT>
__global__ __launch_bounds__(512, 4) void k_lstm_fused(
    const u32x2*  __restrict__ xu,      // 1KB gate-quad rows (scaled units)
    const int*    __restrict__ nbr,     // [N,16]
    const u32x4*  __restrict__ whh,     // 128 frags (A-operand, scaled)
    const u32x4*  __restrict__ wout,    // epilogue A-frags (K=256 concat)
    const float*  __restrict__ bout,    // [NOUT]
    const ushort* __restrict__ x_in,    // [N,128] bf16 (self input)
    OutT*         __restrict__ out,     // [N,NOUT]
    int N)
{
    constexpr int HSTR = 272;                        // 17 x 16B, b128-aligned
    __shared__ alignas(16) char h_lds[2][16 * HSTR]; // 2 x 4.25KB
    __shared__ uint32_t idxs[DEG * 16];              // prescaled byte offsets

    const int tid  = threadIdx.x;
    const int lane = tid & 63;
    const int w    = tid >> 6;
    const int col  = lane & 15;
    const int l4   = lane >> 4;
    const int node0 = blockIdx.x * 16;

    if (tid < DEG * 16) {               // idxs[t*16+m]
        int m = tid & 15, t = tid >> 4;
        int gn = node0 + m; if (gn >= N) gn = N - 1;
        idxs[t * 16 + m] = (uint32_t)nbr[gn * DEG + t] << 10;
    }
    if (tid < 16 * HSTR / 16)           // zero h(-1) = buf[0] (272 u32x4)
        ((u32x4*)h_lds[0])[tid] = u32x4{0u, 0u, 0u, 0u};

    // W_hh A-frags: 64 regs
    u32x4 wreg[4][4];
#pragma unroll
    for (int g = 0; g < 4; ++g)
#pragma unroll
        for (int ks = 0; ks < 4; ++ks)
            wreg[g][ks] = whh[((g * 8 + w) * 4 + ks) * 64 + lane];

    float cst[4];
#pragma unroll
    for (int r = 0; r < 4; ++r) cst[r] = 0.0f;

    const char* xu_c = (const char*)xu;
    const uint32_t goff = (uint32_t)(w * 128 + l4 * 32);  // slice byte in xu row
    const int rd0 = col * HSTR + l4 * 16;                 // + ks*64
    const int wr0 = col * HSTR + w * 32 + l4 * 8;

    __syncthreads();   // idxs + h(-1) zeros visible

    // prologue gather (step 0): 32B contiguous per (node, ch-quad)
    u32x4 vv[2];
    {
        const char* p0 = xu_c + idxs[col] + goff;
        vv[0] = *(const u32x4*)(p0);
        vv[1] = *(const u32x4*)(p0 + 16);
    }

#pragma unroll 1
    for (int t = 0; t < DEG; ++t) {
        const char* hr = h_lds[t & 1];
        char*       hw = h_lds[(t + 1) & 1];

        // ---- acc init: C^T element (ch = w*16+l4*4+q, node = col)
        f32x4 acc[4];
#pragma unroll
        for (int q = 0; q < 4; ++q) {
            uint32_t px = vv[q >> 1][(q & 1) * 2];
            uint32_t py = vv[q >> 1][(q & 1) * 2 + 1];
            acc[0][q] = __uint_as_float(px << 16);
            acc[1][q] = __uint_as_float(px & 0xFFFF0000u);
            acc[2][q] = __uint_as_float(py << 16);
            acc[3][q] = __uint_as_float(py & 0xFFFF0000u);
        }

        // ---- prefetch next step (vv fully consumed)
        if (t + 1 < DEG) {
            const char* p0 = xu_c + idxs[(t + 1) * 16 + col] + goff;
            vv[0] = *(const u32x4*)(p0);
            vv[1] = *(const u32x4*)(p0 + 16);
        }

        // ---- MFMA C^T: A = W_hh frags, B = h(t-1) from LDS (prio-boosted)
        __builtin_amdgcn_s_setprio(1);
#pragma unroll
        for (int ks = 0; ks < 4; ++ks) {
            bf16x8 b = *(const bf16x8*)(hr + rd0 + ks * 64);
#pragma unroll
            for (int g = 0; g < 4; ++g)
                acc[g] = __builtin_amdgcn_mfma_f32_16x16x32_bf16(
                    __builtin_bit_cast(bf16x8, wreg[g][ks]), b, acc[g], 0, 0, 0);
        }
        __builtin_amdgcn_s_setprio(0);

        // ---- cell: full c-path fold + folded output stage (7 trans)
        float hv[4];
#pragma unroll
        for (int q = 0; q < 4; ++q) {
            // c' = [c(1+Ei)(1+Eg) + (1-Eg)(1+Ef)] * rcp((1+Ef)(1+Ei)(1+Eg))
            float Ei = __builtin_amdgcn_exp2f(-acc[0][q]);
            float Eg = __builtin_amdgcn_exp2f(-acc[2][q]);
            float Ef = __builtin_amdgcn_exp2f(-acc[1][q]);
            float p  = (1.0f + Ei) * (1.0f + Eg);
            float num = __fmaf_rn(cst[q], p, (1.0f - Eg) * (1.0f + Ef));
            float cv = num * __builtin_amdgcn_rcpf(p * (1.0f + Ef));
            cst[q] = cv;
            // sig(o)*tanh(c) = (1-Ec) * rcp((1+Eo)(1+Ec))
            float Eo = __builtin_amdgcn_exp2f(-acc[3][q]);
            float Ec = __builtin_amdgcn_exp2f(cv * NEG2_LOG2E);
            hv[q] = (1.0f - Ec) *
                    __builtin_amdgcn_rcpf((1.0f + Eo) * (1.0f + Ec));
        }
        u32x2 hp;
        hp.x = pack2bf16(hv[0], hv[1]);
        hp.y = pack2bf16(hv[2], hv[3]);
        *(u32x2*)(hw + wr0) = hp;

        __syncthreads();   // h(t) visible; WAR-safe via dbuf (1 barrier/step)
    }

    // ---- fused output linear: out = act([x|h] @ [Ws;Wn]^T + b), C^T MFMA
    // h(15) in h_lds[0] (t=15 wrote buf[16&1]=buf[0]).
    if (NOUT == 128 || w < 4) {
        const char* hf = h_lds[0];
        const int otile = (NOUT == 128) ? w : (w & 3);
        const int och0  = otile * 16 + l4 * 4;
        const float4 bq = *(const float4*)(bout + och0);
        const int gn = node0 + col;
        const int gx = (gn < N) ? gn : (N - 1);
        f32x4 acc = {bq.x, bq.y, bq.z, bq.w};
#pragma unroll
        for (int ks = 0; ks < 8; ++ks) {
            u32x4 af = wout[(otile * 8 + ks) * 64 + lane];
            bf16x8 bf_;
            if (ks < 4)
                bf_ = *(const bf16x8*)((const char*)x_in + (size_t)gx * 256 +
                                       ks * 64 + l4 * 16);
            else
                bf_ = *(const bf16x8*)(hf + col * HSTR + (ks - 4) * 64 + l4 * 16);
            acc = __builtin_amdgcn_mfma_f32_16x16x32_bf16(
                __builtin_bit_cast(bf16x8, af), bf_, acc, 0, 0, 0);
        }
        if (gn < N) {
            float av[4];
#pragma unroll
            for (int q = 0; q < 4; ++q)
                av[q] = (ACT == 0) ? fmaxf(acc[q], 0.0f) : fsigmoid(acc[q]);
            if constexpr (sizeof(OutT) == 2) {
                u32x2 o;
                o.x = pack2bf16(av[0], av[1]);
                o.y = pack2bf16(av[2], av[3]);
                *(u32x2*)((ushort*)out + (size_t)gn * NOUT + och0) = o;
            } else {
                f32x4 o = {av[0], av[1], av[2], av[3]};
                *(f32x4*)((float*)out + (size_t)gn * NOUT + och0) = o;
            }
        }
    }
}

extern "C" void kernel_launch(void* const* d_in, const int* in_sizes, int n_in,
                              void* d_out, int out_size, void* d_ws, size_t ws_size,
                              hipStream_t stream)
{
    const float* feats    = (const float*)d_in[0];
    const int*   nbr      = (const int*)  d_in[1];
    const float* w_ih1    = (const float*)d_in[2];
    const float* w_hh1    = (const float*)d_in[3];
    const float* b_ih1    = (const float*)d_in[4];
    const float* b_hh1    = (const float*)d_in[5];
    const float* w_self1  = (const float*)d_in[6];
    const float* w_neigh1 = (const float*)d_in[7];
    const float* b1       = (const float*)d_in[8];
    const float* w_ih2    = (const float*)d_in[9];
    const float* w_hh2    = (const float*)d_in[10];
    const float* b_ih2    = (const float*)d_in[11];
    const float* b_hh2    = (const float*)d_in[12];
    const float* w_self2  = (const float*)d_in[13];
    const float* w_neigh2 = (const float*)d_in[14];
    const float* b2       = (const float*)d_in[15];
    float* out = (float*)d_out;

    const int N = in_sizes[0] / IN;   // 50000
    const long long Nceil = (N + 63) & ~63LL;

    char* ws = (char*)d_ws;
    size_t off = 0;
    auto alloc = [&](size_t bytes) -> void* {
        void* p = (void*)(ws + off);
        off += (bytes + 255) & ~(size_t)255;
        return p;
    };
    u32x4*  wfrag_ih1 = (u32x4*)alloc(8192 * 16);
    u32x4*  wfrag_hh1 = (u32x4*)alloc(8192 * 16);
    u32x4*  wfrag_ih2 = (u32x4*)alloc(8192 * 16);
    u32x4*  wfrag_hh2 = (u32x4*)alloc(8192 * 16);
    u32x4*  wofrag1   = (u32x4*)alloc(4096 * 16);   // 64KB epilogue A-frags L1
    u32x4*  wofrag2   = (u32x4*)alloc(2048 * 16);   // 32KB epilogue A-frags L2
    ushort* feats_bf  = (ushort*)alloc((size_t)N * 128 * 2);
    ushort* out1      = (ushort*)alloc((size_t)N * 128 * 2);
    u32x2*  xu_buf    = (u32x2*)alloc((size_t)Nceil * 128 * 8);   // 51.25MB

    // prep
    k_pack_all<<<dim3(128), dim3(256), 0, stream>>>(w_ih1, wfrag_ih1, w_hh1, wfrag_hh1,
                                                    w_ih2, wfrag_ih2, w_hh2, wfrag_hh2);
    k_pack_out<<<dim3(24), dim3(256), 0, stream>>>(w_self1, w_neigh1, wofrag1,
                                                   w_self2, w_neigh2, wofrag2);

    const int nblk64 = (int)(Nceil / 64);
    const int nblk16 = (N + 15) / 16;   // 3125 (exact for N=50000)

    // layer 1 (k_xu fuses the fp32->bf16 cast and emits feats_bf)
    k_xu<1><<<dim3(nblk64), dim3(256), 0, stream>>>(feats, feats_bf, wfrag_ih1, b_ih1, b_hh1, xu_buf, N);
    k_lstm_fused<128, 0, ushort><<<dim3(nblk16), dim3(512), 0, stream>>>(
        xu_buf, nbr, wfrag_hh1, wofrag1, b1, feats_bf, out1, N);

    // layer 2
    k_xu<0><<<dim3(nblk64), dim3(256), 0, stream>>>(out1, nullptr, wfrag_ih2, b_ih2, b_hh2, xu_buf, N);
    k_lstm_fused<64, 1, float><<<dim3(nblk16), dim3(512), 0, stream>>>(
        xu_buf, nbr, wfrag_hh2, wofrag2, b2, out1, out, N);
}

// Round 15
// 473.478 us; speedup vs baseline: 1.4253x; 1.0009x over previous
//
#include <hip/hip_runtime.h>
#include <cstdint>
#include <cstddef>

// SAGE-LSTM R26: R25 minus setprio (decision-rule revert); cast fusion kept.
// R25 post-mortem: cast-fusion netted ~-9us (win, kept); setprio(1) around
// the MFMA cluster cost +2us/dispatch (lstm 192.0 -> 194.0, tripping the
// pre-committed revert rule) - consistent with the catalog's lockstep-null:
// 8 barrier-locked waves have no phase diversity for the scheduler to exploit.
// R26 = R24's verified lstm loop + R25's k_xu<CVT> fusion. Expected to land
// at the structural ceiling: VALU floor (7 trans/elem) + serial recurrence +
// ~13% grid tail at the 128-reg/4-wave occupancy tier.

constexpr int IN  = 128;
constexpr int DEG = 16;
#define LOG2E       1.4426950408889634f
#define TWO_LOG2E   2.8853900817779268f
#define NEG2_LOG2E -2.8853900817779268f

typedef short bf16x8 __attribute__((ext_vector_type(8)));
typedef float f32x4  __attribute__((ext_vector_type(4)));
typedef float f32x16 __attribute__((ext_vector_type(16)));
typedef unsigned int u32x4 __attribute__((ext_vector_type(4)));
typedef unsigned int u32x2 __attribute__((ext_vector_type(2)));

__device__ __forceinline__ float fsigmoid(float x) {   // unscaled input
    float e = __expf(-x);
    return __builtin_amdgcn_rcpf(1.0f + e);
}
__device__ __forceinline__ uint32_t pack2bf16(float a, float b) {
    uint32_t ua = __float_as_uint(a) + 0x8000u;
    uint32_t ub = __float_as_uint(b) + 0x8000u;
    return (ua >> 16) | (ub & 0xFFFF0000u);
}

// ---------- prep kernels ----------

// Pack all 4 [512 x 128] gate weights into MFMA fragment order, PRE-SCALED:
// gate rows i,f,o (rows 0..255, 384..511) x log2e; gate g (256..383) x 2log2e.
// ih (which 0,2): 32x32x16 B-frag (consumed by k_xu).
// hh (which 1,3): 16x16x32 frag (A-operand in k_lstm_fused).
__global__ void k_pack_all(const float* __restrict__ w0, u32x4* __restrict__ f0,
                           const float* __restrict__ w1, u32x4* __restrict__ f1,
                           const float* __restrict__ w2, u32x4* __restrict__ f2,
                           const float* __restrict__ w3, u32x4* __restrict__ f3) {
    int gt = blockIdx.x * 256 + threadIdx.x;     // 0..32767
    int which = gt >> 13;
    int tid  = gt & 8191;
    const float* wsrc = (which == 0) ? w0 : (which == 1) ? w1 : (which == 2) ? w2 : w3;
    u32x4* frag = (which == 0) ? f0 : (which == 1) ? f1 : (which == 2) ? f2 : f3;
    int lane = tid & 63;
    float v[8];
    int row;
    if ((which & 1) == 0) {
        int tile = (tid >> 6) & 15;
        int kst  = tid >> 10;
        row = tile * 32 + (lane & 31);
        int kbase = kst * 16 + (lane >> 5) * 8;
#pragma unroll
        for (int j = 0; j < 8; ++j) v[j] = wsrc[row * 128 + kbase + j];
    } else {
        int f  = tid >> 6;            // 0..127
        int ks = f & 3;
        int w8 = (f >> 2) & 7;
        int g  = f >> 5;
        row = g * 128 + w8 * 16 + (lane & 15);
        int kbase = ks * 32 + (lane >> 4) * 8;
#pragma unroll
        for (int j = 0; j < 8; ++j) v[j] = wsrc[row * 128 + kbase + j];
    }
    const float sc = ((row >> 7) == 2) ? TWO_LOG2E : LOG2E;
#pragma unroll
    for (int j = 0; j < 8; ++j) v[j] *= sc;
    u32x4 d;
    d.x = pack2bf16(v[0], v[1]);
    d.y = pack2bf16(v[2], v[3]);
    d.z = pack2bf16(v[4], v[5]);
    d.w = pack2bf16(v[6], v[7]);
    frag[tid] = d;
}

// Pack output-linear weights as A-frags over K=256 concat [Wself ; Wneigh].
// (UNSCALED - epilogue activations use natural units.)
__global__ void k_pack_out(const float* __restrict__ ws1, const float* __restrict__ wn1,
                           u32x4* __restrict__ f1,
                           const float* __restrict__ ws2, const float* __restrict__ wn2,
                           u32x4* __restrict__ f2) {
    int t = blockIdx.x * 256 + threadIdx.x;   // 0..6143
    int lane = t & 63;
    int row  = lane & 15;
    int kb   = (lane >> 4) * 8;
    float v[8];
    const float* ws; const float* wn; u32x4* dst; int p;
    if (t < 4096) { ws = ws1; wn = wn1; dst = f1; p = t; }
    else          { ws = ws2; wn = wn2; dst = f2; p = t - 4096; }
    int ks  = (p >> 6) & 7;
    int och = (p >> 9) * 16 + row;
    int kbase = ks * 32 + kb;
#pragma unroll
    for (int j = 0; j < 8; ++j) {
        int k = kbase + j;
        v[j] = (k < 128) ? ws[och * 128 + k] : wn[och * 128 + k - 128];
    }
    u32x4 d;
    d.x = pack2bf16(v[0], v[1]);
    d.y = pack2bf16(v[2], v[3]);
    d.z = pack2bf16(v[4], v[5]);
    d.w = pack2bf16(v[6], v[7]);
    dst[p] = d;
}

// ---------- kernel A: Xu = x @ W_ih^T + (b_ih+b_hh), gate-quad row store ----------
// biases pre-scaled to match the weight scaling (gate g x 2log2e, others x log2e).
// CVT=1: xin is fp32; convert during staging and emit bf16 copy to xbf.
template <int CVT>
__global__ __launch_bounds__(256, 2) void k_xu(
    const void*   __restrict__ xin,     // CVT ? f32[N][128] : bf16[N][128]
    ushort*       __restrict__ xbf,     // CVT=1: bf16 copy out
    const u32x4*  __restrict__ wih,     // 8192 B-frags (32x32 layout, scaled)
    const float*  __restrict__ b_ih,    // [512]
    const float*  __restrict__ b_hh,    // [512]
    u32x2*        __restrict__ xu,      // [Nceil][128] u32x2 (1KB rows)
    int N)
{
    __shared__ u32x4 a_buf[16][66];

    const int tid   = threadIdx.x;
    const int lane  = tid & 63;
    const int w     = tid >> 6;
    const int mrow  = lane & 31;
    const int khalf = lane >> 5;
    const int node0 = blockIdx.x * 64;

    u32x4 wreg[8][4];
#pragma unroll
    for (int kst = 0; kst < 8; ++kst)
#pragma unroll
        for (int g = 0; g < 4; ++g)
            wreg[kst][g] = wih[(kst * 16 + g * 4 + w) * 64 + lane];

    float binit[4];
#pragma unroll
    for (int g = 0; g < 4; ++g) {
        int jj = g * 128 + w * 32 + mrow;
        binit[g] = (b_ih[jj] + b_hh[jj]) * ((g == 2) ? TWO_LOG2E : LOG2E);
    }

    {
        int m_st = tid >> 2, c4 = tid & 3;
        int gn = node0 + m_st; if (gn >= N) gn = N - 1;
        if constexpr (CVT) {
            const float* src = (const float*)xin + (size_t)gn * IN;
#pragma unroll
            for (int q = 0; q < 4; ++q) {
                int kg = q * 4 + c4;
                float4 f0 = *(const float4*)(src + kg * 8);
                float4 f1 = *(const float4*)(src + kg * 8 + 4);
                u32x4 d;
                d.x = pack2bf16(f0.x, f0.y);
                d.y = pack2bf16(f0.z, f0.w);
                d.z = pack2bf16(f1.x, f1.y);
                d.w = pack2bf16(f1.z, f1.w);
                a_buf[kg][m_st] = d;
                *(u32x4*)(xbf + (size_t)gn * IN + kg * 8) = d;
            }
        } else {
            const u32x4* src = (const u32x4*)((const ushort*)xin + (size_t)gn * IN);
#pragma unroll
            for (int q = 0; q < 4; ++q) {
                int kg = q * 4 + c4;
                a_buf[kg][m_st] = src[kg];
            }
        }
    }
    __syncthreads();

    const int coff = w * 32 + mrow;
#pragma unroll 1
    for (int Mt = 0; Mt < 2; ++Mt) {
        f32x16 acc[4];
#pragma unroll
        for (int g = 0; g < 4; ++g)
#pragma unroll
            for (int r = 0; r < 16; ++r) acc[g][r] = binit[g];

#pragma unroll
        for (int kst = 0; kst < 8; ++kst) {
            bf16x8 a = __builtin_bit_cast(bf16x8, a_buf[kst * 2 + khalf][Mt * 32 + mrow]);
#pragma unroll
            for (int g = 0; g < 4; ++g)
                acc[g] = __builtin_amdgcn_mfma_f32_32x32x16_bf16(
                    a, __builtin_bit_cast(bf16x8, wreg[kst][g]), acc[g], 0, 0, 0);
        }

#pragma unroll
        for (int r = 0; r < 16; ++r) {
            int m = Mt * 32 + (r & 3) + 8 * (r >> 2) + 4 * khalf;
            u32x2 d;
            d.x = pack2bf16(acc[0][r], acc[1][r]);
            d.y = pack2bf16(acc[2][r], acc[3][r]);
            xu[(size_t)(node0 + m) * 128 + coff] = d;
        }
    }
}

// ---------- kernel B: recurrent LSTM (C^T, 16-node tiles) + fused out linear ----------
// wave w owns channels [w*16,w*16+16) of ALL 4 gates for 16 nodes; C^T: row =
// channel (l4*4+q), col = node. Lane owns 4 ADJACENT channels of 1 node ->
// shfl-free h pack. h LDS: [node][ch] bf16, row stride 272B (17x16B).
template <int NOUT, int ACT, typename OutT>
__global__ __launch_bounds__(512, 4) void k_lstm_fused(
    const u32x2*  __restrict__ xu,      // 1KB gate-quad rows (scaled units)
    const int*    __restrict__ nbr,     // [N,16]
    const u32x4*  __restrict__ whh,     // 128 frags (A-operand, scaled)
    const u32x4*  __restrict__ wout,    // epilogue A-frags (K=256 concat)
    const float*  __restrict__ bout,    // [NOUT]
    const ushort* __restrict__ x_in,    // [N,128] bf16 (self input)
    OutT*         __restrict__ out,     // [N,NOUT]
    int N)
{
    constexpr int HSTR = 272;                        // 17 x 16B, b128-aligned
    __shared__ alignas(16) char h_lds[2][16 * HSTR]; // 2 x 4.25KB
    __shared__ uint32_t idxs[DEG * 16];              // prescaled byte offsets

    const int tid  = threadIdx.x;
    const int lane = tid & 63;
    const int w    = tid >> 6;
    const int col  = lane & 15;
    const int l4   = lane >> 4;
    const int node0 = blockIdx.x * 16;

    if (tid < DEG * 16) {               // idxs[t*16+m]
        int m = tid & 15, t = tid >> 4;
        int gn = node0 + m; if (gn >= N) gn = N - 1;
        idxs[t * 16 + m] = (uint32_t)nbr[gn * DEG + t] << 10;
    }
    if (tid < 16 * HSTR / 16)           // zero h(-1) = buf[0] (272 u32x4)
        ((u32x4*)h_lds[0])[tid] = u32x4{0u, 0u, 0u, 0u};

    // W_hh A-frags: 64 regs
    u32x4 wreg[4][4];
#pragma unroll
    for (int g = 0; g < 4; ++g)
#pragma unroll
        for (int ks = 0; ks < 4; ++ks)
            wreg[g][ks] = whh[((g * 8 + w) * 4 + ks) * 64 + lane];

    float cst[4];
#pragma unroll
    for (int r = 0; r < 4; ++r) cst[r] = 0.0f;

    const char* xu_c = (const char*)xu;
    const uint32_t goff = (uint32_t)(w * 128 + l4 * 32);  // slice byte in xu row
    const int rd0 = col * HSTR + l4 * 16;                 // + ks*64
    const int wr0 = col * HSTR + w * 32 + l4 * 8;

    __syncthreads();   // idxs + h(-1) zeros visible

    // prologue gather (step 0): 32B contiguous per (node, ch-quad)
    u32x4 vv[2];
    {
        const char* p0 = xu_c + idxs[col] + goff;
        vv[0] = *(const u32x4*)(p0);
        vv[1] = *(const u32x4*)(p0 + 16);
    }

#pragma unroll 1
    for (int t = 0; t < DEG; ++t) {
        const char* hr = h_lds[t & 1];
        char*       hw = h_lds[(t + 1) & 1];

        // ---- acc init: C^T element (ch = w*16+l4*4+q, node = col)
        f32x4 acc[4];
#pragma unroll
        for (int q = 0; q < 4; ++q) {
            uint32_t px = vv[q >> 1][(q & 1) * 2];
            uint32_t py = vv[q >> 1][(q & 1) * 2 + 1];
            acc[0][q] = __uint_as_float(px << 16);
            acc[1][q] = __uint_as_float(px & 0xFFFF0000u);
            acc[2][q] = __uint_as_float(py << 16);
            acc[3][q] = __uint_as_float(py & 0xFFFF0000u);
        }

        // ---- prefetch next step (vv fully consumed)
        if (t + 1 < DEG) {
            const char* p0 = xu_c + idxs[(t + 1) * 16 + col] + goff;
            vv[0] = *(const u32x4*)(p0);
            vv[1] = *(const u32x4*)(p0 + 16);
        }

        // ---- MFMA C^T: A = W_hh frags, B = h(t-1) from LDS
#pragma unroll
        for (int ks = 0; ks < 4; ++ks) {
            bf16x8 b = *(const bf16x8*)(hr + rd0 + ks * 64);
#pragma unroll
            for (int g = 0; g < 4; ++g)
                acc[g] = __builtin_amdgcn_mfma_f32_16x16x32_bf16(
                    __builtin_bit_cast(bf16x8, wreg[g][ks]), b, acc[g], 0, 0, 0);
        }

        // ---- cell: full c-path fold + folded output stage (7 trans)
        float hv[4];
#pragma unroll
        for (int q = 0; q < 4; ++q) {
            // c' = [c(1+Ei)(1+Eg) + (1-Eg)(1+Ef)] * rcp((1+Ef)(1+Ei)(1+Eg))
            float Ei = __builtin_amdgcn_exp2f(-acc[0][q]);
            float Eg = __builtin_amdgcn_exp2f(-acc[2][q]);
            float Ef = __builtin_amdgcn_exp2f(-acc[1][q]);
            float p  = (1.0f + Ei) * (1.0f + Eg);
            float num = __fmaf_rn(cst[q], p, (1.0f - Eg) * (1.0f + Ef));
            float cv = num * __builtin_amdgcn_rcpf(p * (1.0f + Ef));
            cst[q] = cv;
            // sig(o)*tanh(c) = (1-Ec) * rcp((1+Eo)(1+Ec))
            float Eo = __builtin_amdgcn_exp2f(-acc[3][q]);
            float Ec = __builtin_amdgcn_exp2f(cv * NEG2_LOG2E);
            hv[q] = (1.0f - Ec) *
                    __builtin_amdgcn_rcpf((1.0f + Eo) * (1.0f + Ec));
        }
        u32x2 hp;
        hp.x = pack2bf16(hv[0], hv[1]);
        hp.y = pack2bf16(hv[2], hv[3]);
        *(u32x2*)(hw + wr0) = hp;

        __syncthreads();   // h(t) visible; WAR-safe via dbuf (1 barrier/step)
    }

    // ---- fused output linear: out = act([x|h] @ [Ws;Wn]^T + b), C^T MFMA
    // h(15) in h_lds[0] (t=15 wrote buf[16&1]=buf[0]).
    if (NOUT == 128 || w < 4) {
        const char* hf = h_lds[0];
        const int otile = (NOUT == 128) ? w : (w & 3);
        const int och0  = otile * 16 + l4 * 4;
        const float4 bq = *(const float4*)(bout + och0);
        const int gn = node0 + col;
        const int gx = (gn < N) ? gn : (N - 1);
        f32x4 acc = {bq.x, bq.y, bq.z, bq.w};
#pragma unroll
        for (int ks = 0; ks < 8; ++ks) {
            u32x4 af = wout[(otile * 8 + ks) * 64 + lane];
            bf16x8 bf_;
            if (ks < 4)
                bf_ = *(const bf16x8*)((const char*)x_in + (size_t)gx * 256 +
                                       ks * 64 + l4 * 16);
            else
                bf_ = *(const bf16x8*)(hf + col * HSTR + (ks - 4) * 64 + l4 * 16);
            acc = __builtin_amdgcn_mfma_f32_16x16x32_bf16(
                __builtin_bit_cast(bf16x8, af), bf_, acc, 0, 0, 0);
        }
        if (gn < N) {
            float av[4];
#pragma unroll
            for (int q = 0; q < 4; ++q)
                av[q] = (ACT == 0) ? fmaxf(acc[q], 0.0f) : fsigmoid(acc[q]);
            if constexpr (sizeof(OutT) == 2) {
                u32x2 o;
                o.x = pack2bf16(av[0], av[1]);
                o.y = pack2bf16(av[2], av[3]);
                *(u32x2*)((ushort*)out + (size_t)gn * NOUT + och0) = o;
            } else {
                f32x4 o = {av[0], av[1], av[2], av[3]};
                *(f32x4*)((float*)out + (size_t)gn * NOUT + och0) = o;
            }
        }
    }
}

extern "C" void kernel_launch(void* const* d_in, const int* in_sizes, int n_in,
                              void* d_out, int out_size, void* d_ws, size_t ws_size,
                              hipStream_t stream)
{
    const float* feats    = (const float*)d_in[0];
    const int*   nbr      = (const int*)  d_in[1];
    const float* w_ih1    = (const float*)d_in[2];
    const float* w_hh1    = (const float*)d_in[3];
    const float* b_ih1    = (const float*)d_in[4];
    const float* b_hh1    = (const float*)d_in[5];
    const float* w_self1  = (const float*)d_in[6];
    const float* w_neigh1 = (const float*)d_in[7];
    const float* b1       = (const float*)d_in[8];
    const float* w_ih2    = (const float*)d_in[9];
    const float* w_hh2    = (const float*)d_in[10];
    const float* b_ih2    = (const float*)d_in[11];
    const float* b_hh2    = (const float*)d_in[12];
    const float* w_self2  = (const float*)d_in[13];
    const float* w_neigh2 = (const float*)d_in[14];
    const float* b2       = (const float*)d_in[15];
    float* out = (float*)d_out;

    const int N = in_sizes[0] / IN;   // 50000
    const long long Nceil = (N + 63) & ~63LL;

    char* ws = (char*)d_ws;
    size_t off = 0;
    auto alloc = [&](size_t bytes) -> void* {
        void* p = (void*)(ws + off);
        off += (bytes + 255) & ~(size_t)255;
        return p;
    };
    u32x4*  wfrag_ih1 = (u32x4*)alloc(8192 * 16);
    u32x4*  wfrag_hh1 = (u32x4*)alloc(8192 * 16);
    u32x4*  wfrag_ih2 = (u32x4*)alloc(8192 * 16);
    u32x4*  wfrag_hh2 = (u32x4*)alloc(8192 * 16);
    u32x4*  wofrag1   = (u32x4*)alloc(4096 * 16);   // 64KB epilogue A-frags L1
    u32x4*  wofrag2   = (u32x4*)alloc(2048 * 16);   // 32KB epilogue A-frags L2
    ushort* feats_bf  = (ushort*)alloc((size_t)N * 128 * 2);
    ushort* out1      = (ushort*)alloc((size_t)N * 128 * 2);
    u32x2*  xu_buf    = (u32x2*)alloc((size_t)Nceil * 128 * 8);   // 51.25MB

    // prep
    k_pack_all<<<dim3(128), dim3(256), 0, stream>>>(w_ih1, wfrag_ih1, w_hh1, wfrag_hh1,
                                                    w_ih2, wfrag_ih2, w_hh2, wfrag_hh2);
    k_pack_out<<<dim3(24), dim3(256), 0, stream>>>(w_self1, w_neigh1, wofrag1,
                                                   w_self2, w_neigh2, wofrag2);

    const int nblk64 = (int)(Nceil / 64);
    const int nblk16 = (N + 15) / 16;   // 3125 (exact for N=50000)

    // layer 1 (k_xu fuses the fp32->bf16 cast and emits feats_bf)
    k_xu<1><<<dim3(nblk64), dim3(256), 0, stream>>>(feats, feats_bf, wfrag_ih1, b_ih1, b_hh1, xu_buf, N);
    k_lstm_fused<128, 0, ushort><<<dim3(nblk16), dim3(512), 0, stream>>>(
        xu_buf, nbr, wfrag_hh1, wofrag1, b1, feats_bf, out1, N);

    // layer 2
    k_xu<0><<<dim3(nblk64), dim3(256), 0, stream>>>(out1, nullptr, wfrag_ih2, b_ih2, b_hh2, xu_buf, N);
    k_lstm_fused<64, 1, float><<<dim3(nblk16), dim3(512), 0, stream>>>(
        xu_buf, nbr, wfrag_hh2, wofrag2, b2, out1, out, N);
}